// Round 1
// baseline (2621.392 us; speedup 1.0000x reference)
//
#include <hip/hip_runtime.h>
#include <hip/hip_bf16.h>
#include <stdint.h>

// Problem constants
#define B_ 8
#define T_ 10
#define N_ 50
#define IN_ 6
#define H_ 256
#define K_ 4
#define E_ 2450        // N*(N-1)
#define ETILES 77      // ceil(E/32)

typedef __attribute__((ext_vector_type(8))) __bf16 bf16x8;
typedef __attribute__((ext_vector_type(4))) float f32x4;

__device__ __forceinline__ unsigned short f2bf(float x) {
    unsigned int u = __float_as_uint(x);
    u = (u + 0x7fffu + ((u >> 16) & 1u)) >> 16;   // RNE
    return (unsigned short)u;
}
__device__ __forceinline__ float tanh_fast(float x) {
    float e = __expf(2.0f * x);
    return 1.0f - 2.0f / (e + 1.0f);
}
__device__ __forceinline__ float sigmoid_fast(float x) {
    return 1.0f / (1.0f + __expf(-x));
}

__global__ __launch_bounds__(256) void zero_f32(float* p, int n) {
    int i = blockIdx.x * 256 + threadIdx.x;
    if (i < n) p[i] = 0.0f;
}

// Swizzle msg weights (edge types 1..3) into bf16 MFMA B-fragment order:
// W1s[((i*16+nt)*16+kt)*64 + L][j] = w1[i+1][n=nt*16+(L&15)][k=kt*32+(L>>4)*8+j]
__global__ __launch_bounds__(256) void swizzle_weights(
        const float* __restrict__ w1, const float* __restrict__ w2,
        unsigned short* __restrict__ w1s, unsigned short* __restrict__ w2s) {
    const int W1N = 3 * 16 * 16 * 64 * 8;   // 393216
    const int W2N = 3 * 16 * 8 * 64 * 8;    // 196608
    int idx = blockIdx.x * 256 + threadIdx.x;
    if (idx < W1N) {
        int j = idx & 7, L = (idx >> 3) & 63, kt = (idx >> 9) & 15;
        int nt = (idx >> 13) & 15, i = idx >> 17;
        int n = nt * 16 + (L & 15);
        int k = kt * 32 + ((L >> 4) << 3) + j;
        w1s[idx] = f2bf(w1[((size_t)(i + 1) * H_ + n) * (2 * H_) + k]);
    } else if (idx < W1N + W2N) {
        int t = idx - W1N;
        int j = t & 7, L = (t >> 3) & 63, kt = (t >> 9) & 7;
        int nt = (t >> 12) & 15, i = t >> 16;
        int n = nt * 16 + (L & 15);
        int k = kt * 32 + ((L >> 4) << 3) + j;
        w2s[t] = f2bf(w2[((size_t)(i + 1) * H_ + n) * H_ + k]);
    }
}

// Fused edge-message kernel: all_msgs[b,e,h] = sum_ty tanh(tanh(pre@W1^T+b1)@W2^T+b2)*rel/3
// Tile: 32 edges x 256 h per block; 4 waves, wave w owns n-tiles [4w,4w+4), both m-tiles.
__global__ __launch_bounds__(256) void msg_kernel(
        const float* __restrict__ hidden, const float* __restrict__ edges,
        const unsigned short* __restrict__ w1s, const unsigned short* __restrict__ w2s,
        const float* __restrict__ b1, const float* __restrict__ b2,
        float* __restrict__ allm, int t) {
    __shared__ unsigned short preA[32 * 520];   // 32 rows x 512 k, +8 pad
    __shared__ unsigned short m1A[32 * 264];    // 32 rows x 256 k, +8 pad
    __shared__ float relS[32 * 4];

    int b = blockIdx.x / ETILES;
    int e0 = (blockIdx.x % ETILES) * 32;
    int EC = min(32, E_ - e0);
    int tid = threadIdx.x;

    // stage rel factors
    if (tid < 128) {
        int m = tid >> 2, kk = tid & 3;
        float v = 0.0f;
        if (m < EC) v = edges[(((size_t)b * T_ + t) * E_ + (e0 + m)) * K_ + kk];
        relS[m * 4 + kk] = v;
    }
    // stage pre = [hidden[recv], hidden[send]] as bf16 (zero-fill tail rows)
    for (int c = tid; c < 32 * 128; c += 256) {
        int m = c >> 7;
        int kc = (c & 127) << 2;    // 0..508, step 4
        uint2 packed = make_uint2(0u, 0u);
        if (m < EC) {
            int e = e0 + m;
            int s = e / 49;
            int p = e - s * 49;
            int r = p + (p >= s ? 1 : 0);
            int node = (kc < 256) ? r : s;
            int off = kc & 255;
            float4 v = *(const float4*)&hidden[((size_t)b * N_ + node) * H_ + off];
            packed.x = (unsigned)f2bf(v.x) | ((unsigned)f2bf(v.y) << 16);
            packed.y = (unsigned)f2bf(v.z) | ((unsigned)f2bf(v.w) << 16);
        }
        *(uint2*)&preA[m * 520 + kc] = packed;
    }
    __syncthreads();

    int lane = tid & 63;
    int wid = tid >> 6;
    int ntq = wid * 4;
    int col = lane & 15;
    int q = lane >> 4;

    float accAll[2][4][4] = {};
    const bf16x8* w1f = (const bf16x8*)w1s;
    const bf16x8* w2f = (const bf16x8*)w2s;

    for (int ty = 0; ty < 3; ++ty) {
        __syncthreads();   // m1A safe to overwrite
        f32x4 acc[2][4];
        #pragma unroll
        for (int mt = 0; mt < 2; ++mt)
            #pragma unroll
            for (int u = 0; u < 4; ++u) acc[mt][u] = (f32x4){0.f, 0.f, 0.f, 0.f};
        // GEMM1: [32,512] @ W1[ty]^T -> [32,256]
        #pragma unroll
        for (int kt = 0; kt < 16; ++kt) {
            bf16x8 a0 = *(const bf16x8*)&preA[(col) * 520 + kt * 32 + q * 8];
            bf16x8 a1 = *(const bf16x8*)&preA[(16 + col) * 520 + kt * 32 + q * 8];
            #pragma unroll
            for (int u = 0; u < 4; ++u) {
                bf16x8 w = w1f[(size_t)((ty * 16 + ntq + u) * 16 + kt) * 64 + lane];
                acc[0][u] = __builtin_amdgcn_mfma_f32_16x16x32_bf16(a0, w, acc[0][u], 0, 0, 0);
                acc[1][u] = __builtin_amdgcn_mfma_f32_16x16x32_bf16(a1, w, acc[1][u], 0, 0, 0);
            }
        }
        #pragma unroll
        for (int mt = 0; mt < 2; ++mt)
            #pragma unroll
            for (int u = 0; u < 4; ++u) {
                float bias = b1[(ty + 1) * H_ + (ntq + u) * 16 + col];
                #pragma unroll
                for (int r = 0; r < 4; ++r)
                    m1A[(mt * 16 + q * 4 + r) * 264 + (ntq + u) * 16 + col] =
                        f2bf(tanh_fast(acc[mt][u][r] + bias));
            }
        __syncthreads();
        // GEMM2: [32,256] @ W2[ty]^T -> [32,256]
        #pragma unroll
        for (int mt = 0; mt < 2; ++mt)
            #pragma unroll
            for (int u = 0; u < 4; ++u) acc[mt][u] = (f32x4){0.f, 0.f, 0.f, 0.f};
        #pragma unroll
        for (int kt = 0; kt < 8; ++kt) {
            bf16x8 a0 = *(const bf16x8*)&m1A[(col) * 264 + kt * 32 + q * 8];
            bf16x8 a1 = *(const bf16x8*)&m1A[(16 + col) * 264 + kt * 32 + q * 8];
            #pragma unroll
            for (int u = 0; u < 4; ++u) {
                bf16x8 w = w2f[(size_t)((ty * 16 + ntq + u) * 8 + kt) * 64 + lane];
                acc[0][u] = __builtin_amdgcn_mfma_f32_16x16x32_bf16(a0, w, acc[0][u], 0, 0, 0);
                acc[1][u] = __builtin_amdgcn_mfma_f32_16x16x32_bf16(a1, w, acc[1][u], 0, 0, 0);
            }
        }
        #pragma unroll
        for (int mt = 0; mt < 2; ++mt)
            #pragma unroll
            for (int u = 0; u < 4; ++u) {
                float bias = b2[(ty + 1) * H_ + (ntq + u) * 16 + col];
                #pragma unroll
                for (int r = 0; r < 4; ++r) {
                    int m = mt * 16 + q * 4 + r;
                    accAll[mt][u][r] +=
                        tanh_fast(acc[mt][u][r] + bias) * relS[m * 4 + ty + 1] * (1.0f / 3.0f);
                }
            }
    }
    // write all_msgs
    #pragma unroll
    for (int mt = 0; mt < 2; ++mt)
        #pragma unroll
        for (int u = 0; u < 4; ++u)
            #pragma unroll
            for (int r = 0; r < 4; ++r) {
                int m = mt * 16 + q * 4 + r;
                if (m < EC)
                    allm[((size_t)b * E_ + e0 + m) * H_ + (ntq + u) * 16 + col] = accAll[mt][u][r];
            }
}

// agg[b,n,h] = (1/49) * sum over senders i!=n of all_msgs[b, e(i,n), h]
__global__ __launch_bounds__(256) void agg_kernel(const float* __restrict__ allm,
                                                  float* __restrict__ agg) {
    int idx = blockIdx.x * 256 + threadIdx.x;   // B*N*H
    int h = idx & 255;
    int n = (idx >> 8) % N_;
    int b = idx / (256 * N_);
    float s = 0.0f;
    for (int i = 0; i < N_; ++i) {
        if (i == n) continue;
        int e = i * 49 + (n < i ? n : n - 1);
        s += allm[((size_t)b * E_ + e) * H_ + h];
    }
    agg[idx] = s * (1.0f / 49.0f);
}

// GRU gate update + output MLP. Block = (n, half-of-batch): 4 rows per block.
__global__ __launch_bounds__(256) void gru_kernel(
        const float* __restrict__ inputs, const float* __restrict__ agg,
        float* __restrict__ hidden,
        const float* __restrict__ w_hr, const float* __restrict__ w_hi,
        const float* __restrict__ w_hh,
        const float* __restrict__ w_ir, const float* __restrict__ b_ir,
        const float* __restrict__ w_ii, const float* __restrict__ b_ii,
        const float* __restrict__ w_in, const float* __restrict__ b_in,
        const float* __restrict__ w_o1, const float* __restrict__ b_o1,
        const float* __restrict__ w_o2, const float* __restrict__ b_o2,
        const float* __restrict__ w_o3, const float* __restrict__ b_o3,
        float* __restrict__ out, int t) {
    __shared__ float aggL[4][256];
    __shared__ float hnL[4][256];
    __shared__ float p1L[4][256];
    __shared__ float p2L[4][256];
    __shared__ float insL[4][8];

    int n = blockIdx.x >> 1;
    int bg = blockIdx.x & 1;
    int h = threadIdx.x;

    const float* src = (t == 0) ? inputs : out;
    int tt = (t == 0) ? 0 : (t - 1);

    #pragma unroll
    for (int r = 0; r < 4; ++r) {
        int b = bg * 4 + r;
        aggL[r][h] = agg[((size_t)b * N_ + n) * H_ + h];
    }
    if (h < 24) {
        int r = h / 6, c = h % 6;
        int b = bg * 4 + r;
        insL[r][c] = src[(((size_t)b * T_ + tt) * N_ + n) * IN_ + c];
    }
    __syncthreads();

    float accR[4] = {0, 0, 0, 0}, accI[4] = {0, 0, 0, 0}, accN[4] = {0, 0, 0, 0};
    for (int k = 0; k < 256; k += 4) {
        float4 whr = *(const float4*)&w_hr[h * 256 + k];
        float4 whi = *(const float4*)&w_hi[h * 256 + k];
        float4 whh = *(const float4*)&w_hh[h * 256 + k];
        #pragma unroll
        for (int r = 0; r < 4; ++r) {
            float a0 = aggL[r][k], a1 = aggL[r][k + 1], a2 = aggL[r][k + 2], a3 = aggL[r][k + 3];
            accR[r] += whr.x * a0 + whr.y * a1 + whr.z * a2 + whr.w * a3;
            accI[r] += whi.x * a0 + whi.y * a1 + whi.z * a2 + whi.w * a3;
            accN[r] += whh.x * a0 + whh.y * a1 + whh.z * a2 + whh.w * a3;
        }
    }
    float bir = b_ir[h], bii = b_ii[h], bin_ = b_in[h];
    #pragma unroll
    for (int r = 0; r < 4; ++r) {
        int b = bg * 4 + r;
        float xr = bir, xi = bii, xn = bin_;
        #pragma unroll
        for (int c = 0; c < 6; ++c) {
            float iv = insL[r][c];
            xr += w_ir[h * 6 + c] * iv;
            xi += w_ii[h * 6 + c] * iv;
            xn += w_in[h * 6 + c] * iv;
        }
        float rg = sigmoid_fast(xr + accR[r]);
        float ig = sigmoid_fast(xi + accI[r]);
        float nn = tanh_fast(xn + rg * accN[r]);
        size_t hoff = ((size_t)b * N_ + n) * H_ + h;
        float hold = hidden[hoff];
        float hnew = (1.0f - ig) * nn + ig * hold;
        hidden[hoff] = hnew;
        hnL[r][h] = hnew;
    }
    __syncthreads();
    {
        float bo = b_o1[h];
        float p1a[4] = {bo, bo, bo, bo};
        for (int k = 0; k < 256; k += 4) {
            float4 w = *(const float4*)&w_o1[h * 256 + k];
            #pragma unroll
            for (int r = 0; r < 4; ++r)
                p1a[r] += w.x * hnL[r][k] + w.y * hnL[r][k + 1] + w.z * hnL[r][k + 2] +
                          w.w * hnL[r][k + 3];
        }
        #pragma unroll
        for (int r = 0; r < 4; ++r) p1L[r][h] = fmaxf(p1a[r], 0.0f);
    }
    __syncthreads();
    {
        float bo = b_o2[h];
        float p2a[4] = {bo, bo, bo, bo};
        for (int k = 0; k < 256; k += 4) {
            float4 w = *(const float4*)&w_o2[h * 256 + k];
            #pragma unroll
            for (int r = 0; r < 4; ++r)
                p2a[r] += w.x * p1L[r][k] + w.y * p1L[r][k + 1] + w.z * p1L[r][k + 2] +
                          w.w * p1L[r][k + 3];
        }
        #pragma unroll
        for (int r = 0; r < 4; ++r) p2L[r][h] = fmaxf(p2a[r], 0.0f);
    }
    __syncthreads();
    if (h < 24) {
        int r = h / 6, c = h % 6;
        int b = bg * 4 + r;
        float acc = b_o3[c];
        for (int k = 0; k < 256; ++k) acc += w_o3[c * 256 + k] * p2L[r][k];
        out[(((size_t)b * T_ + t) * N_ + n) * IN_ + c] = insL[r][c] + acc;
    }
}

extern "C" void kernel_launch(void* const* d_in, const int* in_sizes, int n_in,
                              void* d_out, int out_size, void* d_ws, size_t ws_size,
                              hipStream_t stream) {
    const float* inputs = (const float*)d_in[0];
    const float* edges  = (const float*)d_in[1];
    const float* msg_w1 = (const float*)d_in[2];
    const float* msg_b1 = (const float*)d_in[3];
    const float* msg_w2 = (const float*)d_in[4];
    const float* msg_b2 = (const float*)d_in[5];
    const float* w_hr = (const float*)d_in[6];
    const float* w_hi = (const float*)d_in[7];
    const float* w_hh = (const float*)d_in[8];
    const float* w_ir = (const float*)d_in[9];
    const float* b_ir = (const float*)d_in[10];
    const float* w_ii = (const float*)d_in[11];
    const float* b_ii = (const float*)d_in[12];
    const float* w_in = (const float*)d_in[13];
    const float* b_in = (const float*)d_in[14];
    const float* w_o1 = (const float*)d_in[15];
    const float* b_o1 = (const float*)d_in[16];
    const float* w_o2 = (const float*)d_in[17];
    const float* b_o2 = (const float*)d_in[18];
    const float* w_o3 = (const float*)d_in[19];
    const float* b_o3 = (const float*)d_in[20];
    float* out = (float*)d_out;

    char* ws = (char*)d_ws;
    float* hidden        = (float*)(ws);                  // 409,600 B
    float* agg           = (float*)(ws + 409600);         // 409,600 B
    float* allm          = (float*)(ws + 819200);         // 20,070,400 B
    unsigned short* w1s  = (unsigned short*)(ws + 20889600);  // 786,432 B
    unsigned short* w2s  = (unsigned short*)(ws + 21676032);  // 393,216 B

    zero_f32<<<dim3((B_ * N_ * H_) / 256), dim3(256), 0, stream>>>(hidden, B_ * N_ * H_);
    swizzle_weights<<<dim3((393216 + 196608 + 255) / 256), dim3(256), 0, stream>>>(
        msg_w1, msg_w2, w1s, w2s);

    for (int t = 0; t < T_; ++t) {
        msg_kernel<<<dim3(B_ * ETILES), dim3(256), 0, stream>>>(
            hidden, edges, w1s, w2s, msg_b1, msg_b2, allm, t);
        agg_kernel<<<dim3((B_ * N_ * H_) / 256), dim3(256), 0, stream>>>(allm, agg);
        gru_kernel<<<dim3(N_ * 2), dim3(256), 0, stream>>>(
            inputs, agg, hidden, w_hr, w_hi, w_hh, w_ir, b_ir, w_ii, b_ii, w_in, b_in,
            w_o1, b_o1, w_o2, b_o2, w_o3, b_o3, out, t);
    }
}

// Round 2
// 902.210 us; speedup vs baseline: 2.9055x; 2.9055x over previous
//
#include <hip/hip_runtime.h>
#include <hip/hip_bf16.h>
#include <stdint.h>

#define B_ 8
#define T_ 10
#define N_ 50
#define IN_ 6
#define H_ 256
#define K_ 4
#define E_ 2450

typedef __attribute__((ext_vector_type(8))) __bf16 bf16x8;
typedef __attribute__((ext_vector_type(4))) float f32x4;

__device__ __forceinline__ unsigned short f2bf(float x) {
    unsigned int u = __float_as_uint(x);
    u = (u + 0x7fffu + ((u >> 16) & 1u)) >> 16;   // RNE
    return (unsigned short)u;
}
__device__ __forceinline__ float tanh_fast(float x) {
    float e = __expf(2.0f * x);
    return 1.0f - 2.0f / (e + 1.0f);
}
__device__ __forceinline__ float sigmoid_fast(float x) {
    return 1.0f / (1.0f + __expf(-x));
}
__device__ __forceinline__ void unpk8(uint4 u, float* w) {
    w[0] = __uint_as_float(u.x << 16); w[1] = __uint_as_float(u.x & 0xffff0000u);
    w[2] = __uint_as_float(u.y << 16); w[3] = __uint_as_float(u.y & 0xffff0000u);
    w[4] = __uint_as_float(u.z << 16); w[5] = __uint_as_float(u.z & 0xffff0000u);
    w[6] = __uint_as_float(u.w << 16); w[7] = __uint_as_float(u.w & 0xffff0000u);
}

__global__ __launch_bounds__(256) void zero_ws(unsigned int* p, int n) {
    int i = blockIdx.x * 256 + threadIdx.x;
    if (i < n) p[i] = 0u;
}

// Swizzle msg weights (types 1..3) into MFMA B-frag order + convert GRU weights to bf16.
__global__ __launch_bounds__(256) void swizzle_weights(
        const float* __restrict__ w1, const float* __restrict__ w2,
        const float* __restrict__ whr, const float* __restrict__ whi,
        const float* __restrict__ whh, const float* __restrict__ wo1,
        const float* __restrict__ wo2,
        unsigned short* __restrict__ w1s, unsigned short* __restrict__ w2s,
        unsigned short* __restrict__ gruw) {
    const int W1N = 3 * 16 * 16 * 64 * 8;   // 393216
    const int W2N = 3 * 16 * 8 * 64 * 8;    // 196608
    int idx = blockIdx.x * 256 + threadIdx.x;
    if (idx < W1N) {
        int j = idx & 7, L = (idx >> 3) & 63, kt = (idx >> 9) & 15;
        int nt = (idx >> 13) & 15, i = idx >> 17;
        int n = nt * 16 + (L & 15);
        int k = kt * 32 + ((L >> 4) << 3) + j;
        w1s[idx] = f2bf(w1[((size_t)(i + 1) * H_ + n) * (2 * H_) + k]);
    } else if (idx < W1N + W2N) {
        int t = idx - W1N;
        int j = t & 7, L = (t >> 3) & 63, kt = (t >> 9) & 7;
        int nt = (t >> 12) & 15, i = t >> 16;
        int n = nt * 16 + (L & 15);
        int k = kt * 32 + ((L >> 4) << 3) + j;
        w2s[t] = f2bf(w2[((size_t)(i + 1) * H_ + n) * H_ + k]);
    } else if (idx < W1N + W2N + 5 * 65536) {
        int t = idx - (W1N + W2N);
        int g = t >> 16, e = t & 65535;
        const float* src = (g == 0) ? whr : (g == 1) ? whi : (g == 2) ? whh
                          : (g == 3) ? wo1 : wo2;
        gruw[t] = f2bf(src[e]);
    }
}

// U/V per node: UV[(row*3+ty)*512 + half*256 + c] = sum_k hidden[row][k]*W1[ty+1][c][half*256+k]
// Grid: 25 m-tiles x 6 (ty,half). Block 256 thr = 4 waves; wave w owns n-tiles {4w..4w+3}.
__global__ __launch_bounds__(256) void uv_kernel(
        const unsigned short* __restrict__ hb, const unsigned short* __restrict__ w1s,
        float* __restrict__ UV) {
    int mm = blockIdx.x / 6;
    int tyh = blockIdx.x % 6;
    int ty = tyh >> 1, half = tyh & 1;
    int lane = threadIdx.x & 63, wid = threadIdx.x >> 6;
    int col = lane & 15, q = lane >> 4;
    const bf16x8* w1f = (const bf16x8*)w1s;

    f32x4 acc[4];
    #pragma unroll
    for (int u = 0; u < 4; ++u) acc[u] = (f32x4){0.f, 0.f, 0.f, 0.f};
    #pragma unroll
    for (int kt = 0; kt < 8; ++kt) {
        bf16x8 a = *(const bf16x8*)&hb[(size_t)(mm * 16 + col) * H_ + kt * 32 + q * 8];
        #pragma unroll
        for (int u = 0; u < 4; ++u) {
            bf16x8 w = w1f[(size_t)((ty * 16 + wid * 4 + u) * 16 + half * 8 + kt) * 64 + lane];
            acc[u] = __builtin_amdgcn_mfma_f32_16x16x32_bf16(a, w, acc[u], 0, 0, 0);
        }
    }
    #pragma unroll
    for (int u = 0; u < 4; ++u)
        #pragma unroll
        for (int r = 0; r < 4; ++r)
            UV[((size_t)(mm * 16 + q * 4 + r) * 3 + ty) * 512 + half * 256 +
               (wid * 4 + u) * 16 + col] = acc[u][r];
}

// Fused m1-build + GEMM2 + sender-reduction. Block = (ty, b, recv r).
// m1[i][c] = tanh(U[r][c] + V[s_i][c] + b1), i over 49 senders; GEMM2 -> tanh*rel;
// reduce over senders -> aggP[ty][b*N+r][h].
__global__ __launch_bounds__(256) void msgagg_kernel(
        const float* __restrict__ UV, const float* __restrict__ edges,
        const unsigned short* __restrict__ w2s,
        const float* __restrict__ b1, const float* __restrict__ b2,
        float* __restrict__ aggP, int t) {
    __shared__ unsigned short m1A[64 * 264];
    __shared__ float relS[64];

    int ty = blockIdx.x / 400;
    int rem = blockIdx.x - ty * 400;
    int b = rem / 50;
    int r = rem - b * 50;
    int tid = threadIdx.x;

    if (tid < 64) {
        float v = 0.0f;
        if (tid < 49) {
            int s = tid + (tid >= r ? 1 : 0);
            int e = s * 49 + (r > s ? r - 1 : r);
            v = edges[(((size_t)b * T_ + t) * E_ + e) * K_ + (ty + 1)];
        }
        relS[tid] = v;
    }
    // zero pad rows 49..63
    #pragma unroll
    for (int c = tid; c < 15 * 256; c += 256) m1A[(49 + (c >> 8)) * 264 + (c & 255)] = 0;
    // stage m1 rows 0..48 (thread owns column tid)
    {
        float urb = UV[((size_t)(b * N_ + r) * 3 + ty) * 512 + tid] + b1[(ty + 1) * H_ + tid];
        #pragma unroll 7
        for (int i = 0; i < 49; ++i) {
            int s = i + (i >= r ? 1 : 0);
            float v = UV[((size_t)(b * N_ + s) * 3 + ty) * 512 + 256 + tid];
            m1A[i * 264 + tid] = f2bf(tanh_fast(urb + v));
        }
    }
    __syncthreads();

    int lane = tid & 63, wid = tid >> 6;
    int col = lane & 15, q = lane >> 4;
    const bf16x8* w2f = (const bf16x8*)w2s;

    f32x4 acc[4][4];
    #pragma unroll
    for (int mt = 0; mt < 4; ++mt)
        #pragma unroll
        for (int u = 0; u < 4; ++u) acc[mt][u] = (f32x4){0.f, 0.f, 0.f, 0.f};

    #pragma unroll
    for (int kt = 0; kt < 8; ++kt) {
        bf16x8 a0 = *(const bf16x8*)&m1A[(col) * 264 + kt * 32 + q * 8];
        bf16x8 a1 = *(const bf16x8*)&m1A[(16 + col) * 264 + kt * 32 + q * 8];
        bf16x8 a2 = *(const bf16x8*)&m1A[(32 + col) * 264 + kt * 32 + q * 8];
        bf16x8 a3 = *(const bf16x8*)&m1A[(48 + col) * 264 + kt * 32 + q * 8];
        #pragma unroll
        for (int u = 0; u < 4; ++u) {
            bf16x8 w = w2f[(size_t)((ty * 16 + wid * 4 + u) * 8 + kt) * 64 + lane];
            acc[0][u] = __builtin_amdgcn_mfma_f32_16x16x32_bf16(a0, w, acc[0][u], 0, 0, 0);
            acc[1][u] = __builtin_amdgcn_mfma_f32_16x16x32_bf16(a1, w, acc[1][u], 0, 0, 0);
            acc[2][u] = __builtin_amdgcn_mfma_f32_16x16x32_bf16(a2, w, acc[2][u], 0, 0, 0);
            acc[3][u] = __builtin_amdgcn_mfma_f32_16x16x32_bf16(a3, w, acc[3][u], 0, 0, 0);
        }
    }
    #pragma unroll
    for (int u = 0; u < 4; ++u) {
        float bias = b2[(ty + 1) * H_ + (wid * 4 + u) * 16 + col];
        float sum = 0.0f;
        #pragma unroll
        for (int mt = 0; mt < 4; ++mt)
            #pragma unroll
            for (int rg = 0; rg < 4; ++rg) {
                int row = mt * 16 + q * 4 + rg;
                sum += tanh_fast(acc[mt][u][rg] + bias) * relS[row];
            }
        sum += __shfl_xor(sum, 16);
        sum += __shfl_xor(sum, 32);
        if (lane < 16)
            aggP[(size_t)ty * (B_ * N_ * H_) + (size_t)(b * N_ + r) * H_ +
                 (wid * 4 + u) * 16 + col] = sum * (1.0f / 3.0f);
    }
}

// GRU gate update + output MLP. 4 batch rows per block, bf16 weights.
__global__ __launch_bounds__(256) void gru_kernel(
        const float* __restrict__ inputs, const float* __restrict__ aggP,
        float* __restrict__ hidden, unsigned short* __restrict__ hidden_bf,
        const unsigned short* __restrict__ gruw,
        const float* __restrict__ w_ir, const float* __restrict__ b_ir,
        const float* __restrict__ w_ii, const float* __restrict__ b_ii,
        const float* __restrict__ w_in, const float* __restrict__ b_in,
        const float* __restrict__ b_o1, const float* __restrict__ b_o2,
        const float* __restrict__ w_o3, const float* __restrict__ b_o3,
        float* __restrict__ out, int t) {
    __shared__ float aggL[4][256];
    __shared__ float hnL[4][256];
    __shared__ float p1L[4][256];
    __shared__ float p2L[4][256];
    __shared__ float insL[4][8];

    int n = blockIdx.x >> 1;
    int bg = blockIdx.x & 1;
    int h = threadIdx.x;

    const unsigned short* whr = gruw;
    const unsigned short* whi = gruw + 65536;
    const unsigned short* whh = gruw + 2 * 65536;
    const unsigned short* wo1 = gruw + 3 * 65536;
    const unsigned short* wo2 = gruw + 4 * 65536;

    const float* src = (t == 0) ? inputs : out;
    int tt = (t == 0) ? 0 : (t - 1);
    const int AP = B_ * N_ * H_;

    #pragma unroll
    for (int r = 0; r < 4; ++r) {
        int bb = bg * 4 + r;
        size_t idx = (size_t)(bb * N_ + n) * H_ + h;
        aggL[r][h] = (aggP[idx] + aggP[AP + idx] + aggP[2 * AP + idx]) * (1.0f / 49.0f);
    }
    if (h < 24) {
        int r = h / 6, c = h % 6;
        int bb = bg * 4 + r;
        insL[r][c] = src[(((size_t)bb * T_ + tt) * N_ + n) * IN_ + c];
    }
    __syncthreads();

    float accR[4] = {0, 0, 0, 0}, accI[4] = {0, 0, 0, 0}, accN[4] = {0, 0, 0, 0};
    for (int k = 0; k < 256; k += 8) {
        uint4 uhr = *(const uint4*)&whr[h * 256 + k];
        uint4 uhi = *(const uint4*)&whi[h * 256 + k];
        uint4 uhh = *(const uint4*)&whh[h * 256 + k];
        float wr[8], wi[8], wh[8];
        unpk8(uhr, wr); unpk8(uhi, wi); unpk8(uhh, wh);
        #pragma unroll
        for (int r = 0; r < 4; ++r) {
            #pragma unroll
            for (int j = 0; j < 8; ++j) {
                float a = aggL[r][k + j];
                accR[r] += wr[j] * a;
                accI[r] += wi[j] * a;
                accN[r] += wh[j] * a;
            }
        }
    }
    float bir = b_ir[h], bii = b_ii[h], bin_ = b_in[h];
    #pragma unroll
    for (int r = 0; r < 4; ++r) {
        int bb = bg * 4 + r;
        float xr = bir, xi = bii, xn = bin_;
        #pragma unroll
        for (int c = 0; c < 6; ++c) {
            float iv = insL[r][c];
            xr += w_ir[h * 6 + c] * iv;
            xi += w_ii[h * 6 + c] * iv;
            xn += w_in[h * 6 + c] * iv;
        }
        float rg = sigmoid_fast(xr + accR[r]);
        float ig = sigmoid_fast(xi + accI[r]);
        float nn = tanh_fast(xn + rg * accN[r]);
        size_t hoff = (size_t)(bb * N_ + n) * H_ + h;
        float hold = hidden[hoff];
        float hnew = (1.0f - ig) * nn + ig * hold;
        hidden[hoff] = hnew;
        hidden_bf[hoff] = f2bf(hnew);
        hnL[r][h] = hnew;
    }
    __syncthreads();
    {
        float bo = b_o1[h];
        float p1a[4] = {bo, bo, bo, bo};
        for (int k = 0; k < 256; k += 8) {
            uint4 uw = *(const uint4*)&wo1[h * 256 + k];
            float w[8];
            unpk8(uw, w);
            #pragma unroll
            for (int r = 0; r < 4; ++r)
                #pragma unroll
                for (int j = 0; j < 8; ++j) p1a[r] += w[j] * hnL[r][k + j];
        }
        #pragma unroll
        for (int r = 0; r < 4; ++r) p1L[r][h] = fmaxf(p1a[r], 0.0f);
    }
    __syncthreads();
    {
        float bo = b_o2[h];
        float p2a[4] = {bo, bo, bo, bo};
        for (int k = 0; k < 256; k += 8) {
            uint4 uw = *(const uint4*)&wo2[h * 256 + k];
            float w[8];
            unpk8(uw, w);
            #pragma unroll
            for (int r = 0; r < 4; ++r)
                #pragma unroll
                for (int j = 0; j < 8; ++j) p2a[r] += w[j] * p1L[r][k + j];
        }
        #pragma unroll
        for (int r = 0; r < 4; ++r) p2L[r][h] = fmaxf(p2a[r], 0.0f);
    }
    __syncthreads();
    if (h < 24) {
        int r = h / 6, c = h % 6;
        int bb = bg * 4 + r;
        float acc = b_o3[c];
        for (int k = 0; k < 256; ++k) acc += w_o3[c * 256 + k] * p2L[r][k];
        out[(((size_t)bb * T_ + t) * N_ + n) * IN_ + c] = insL[r][c] + acc;
    }
}

extern "C" void kernel_launch(void* const* d_in, const int* in_sizes, int n_in,
                              void* d_out, int out_size, void* d_ws, size_t ws_size,
                              hipStream_t stream) {
    const float* inputs = (const float*)d_in[0];
    const float* edges  = (const float*)d_in[1];
    const float* msg_w1 = (const float*)d_in[2];
    const float* msg_b1 = (const float*)d_in[3];
    const float* msg_w2 = (const float*)d_in[4];
    const float* msg_b2 = (const float*)d_in[5];
    const float* w_hr = (const float*)d_in[6];
    const float* w_hi = (const float*)d_in[7];
    const float* w_hh = (const float*)d_in[8];
    const float* w_ir = (const float*)d_in[9];
    const float* b_ir = (const float*)d_in[10];
    const float* w_ii = (const float*)d_in[11];
    const float* b_ii = (const float*)d_in[12];
    const float* w_in = (const float*)d_in[13];
    const float* b_in = (const float*)d_in[14];
    const float* w_o1 = (const float*)d_in[15];
    const float* b_o1 = (const float*)d_in[16];
    const float* w_o2 = (const float*)d_in[17];
    const float* b_o2 = (const float*)d_in[18];
    const float* w_o3 = (const float*)d_in[19];
    const float* b_o3 = (const float*)d_in[20];
    float* out = (float*)d_out;

    char* ws = (char*)d_ws;
    float* hidden            = (float*)(ws);                       // 409,600 B
    unsigned short* hidden_bf= (unsigned short*)(ws + 409600);     // 204,800 B
    float* UV                = (float*)(ws + 614400);              // 2,457,600 B
    float* aggP              = (float*)(ws + 3072000);             // 1,228,800 B
    unsigned short* w1s      = (unsigned short*)(ws + 4300800);    // 786,432 B
    unsigned short* w2s      = (unsigned short*)(ws + 5087232);    // 393,216 B
    unsigned short* gruw     = (unsigned short*)(ws + 5480448);    // 655,360 B

    // zero hidden + hidden_bf (contiguous 614,400 B = 153,600 words)
    zero_ws<<<dim3(600), dim3(256), 0, stream>>>((unsigned int*)ws, 153600);
    swizzle_weights<<<dim3(3584), dim3(256), 0, stream>>>(
        msg_w1, msg_w2, w_hr, w_hi, w_hh, w_o1, w_o2, w1s, w2s, gruw);

    for (int t = 0; t < T_; ++t) {
        uv_kernel<<<dim3(150), dim3(256), 0, stream>>>(hidden_bf, w1s, UV);
        msgagg_kernel<<<dim3(1200), dim3(256), 0, stream>>>(
            UV, edges, w2s, msg_b1, msg_b2, aggP, t);
        gru_kernel<<<dim3(100), dim3(256), 0, stream>>>(
            inputs, aggP, hidden, hidden_bf, gruw,
            w_ir, b_ir, w_ii, b_ii, w_in, b_in, b_o1, b_o2, w_o3, b_o3, out, t);
    }
}

// Round 3
// 861.088 us; speedup vs baseline: 3.0443x; 1.0478x over previous
//
#include <hip/hip_runtime.h>
#include <hip/hip_bf16.h>
#include <stdint.h>

#define B_ 8
#define T_ 10
#define N_ 50
#define IN_ 6
#define H_ 256
#define K_ 4
#define E_ 2450

typedef __attribute__((ext_vector_type(8))) __bf16 bf16x8;
typedef __attribute__((ext_vector_type(4))) float f32x4;

__device__ __forceinline__ unsigned short f2bf(float x) {
    unsigned int u = __float_as_uint(x);
    u = (u + 0x7fffu + ((u >> 16) & 1u)) >> 16;   // RNE
    return (unsigned short)u;
}
__device__ __forceinline__ unsigned pk2(float a, float b) {
    return (unsigned)f2bf(a) | ((unsigned)f2bf(b) << 16);
}
__device__ __forceinline__ float tanh_fast(float x) {
    float e = __expf(2.0f * x);
    return 1.0f - 2.0f / (e + 1.0f);
}
__device__ __forceinline__ float sigmoid_fast(float x) {
    return 1.0f / (1.0f + __expf(-x));
}
__device__ __forceinline__ void unpk8(uint4 u, float* w) {
    w[0] = __uint_as_float(u.x << 16); w[1] = __uint_as_float(u.x & 0xffff0000u);
    w[2] = __uint_as_float(u.y << 16); w[3] = __uint_as_float(u.y & 0xffff0000u);
    w[4] = __uint_as_float(u.z << 16); w[5] = __uint_as_float(u.z & 0xffff0000u);
    w[6] = __uint_as_float(u.w << 16); w[7] = __uint_as_float(u.w & 0xffff0000u);
}

__global__ __launch_bounds__(256) void zero_ws(unsigned int* p, int n) {
    int i = blockIdx.x * 256 + threadIdx.x;
    if (i < n) p[i] = 0u;
}

// Swizzle msg weights (types 1..3) into MFMA B-frag order + convert GRU weights to bf16.
__global__ __launch_bounds__(256) void swizzle_weights(
        const float* __restrict__ w1, const float* __restrict__ w2,
        const float* __restrict__ whr, const float* __restrict__ whi,
        const float* __restrict__ whh, const float* __restrict__ wo1,
        const float* __restrict__ wo2,
        unsigned short* __restrict__ w1s, unsigned short* __restrict__ w2s,
        unsigned short* __restrict__ gruw) {
    const int W1N = 3 * 16 * 16 * 64 * 8;   // 393216
    const int W2N = 3 * 16 * 8 * 64 * 8;    // 196608
    int idx = blockIdx.x * 256 + threadIdx.x;
    if (idx < W1N) {
        int j = idx & 7, L = (idx >> 3) & 63, kt = (idx >> 9) & 15;
        int nt = (idx >> 13) & 15, i = idx >> 17;
        int n = nt * 16 + (L & 15);
        int k = kt * 32 + ((L >> 4) << 3) + j;
        w1s[idx] = f2bf(w1[((size_t)(i + 1) * H_ + n) * (2 * H_) + k]);
    } else if (idx < W1N + W2N) {
        int t = idx - W1N;
        int j = t & 7, L = (t >> 3) & 63, kt = (t >> 9) & 7;
        int nt = (t >> 12) & 15, i = t >> 16;
        int n = nt * 16 + (L & 15);
        int k = kt * 32 + ((L >> 4) << 3) + j;
        w2s[t] = f2bf(w2[((size_t)(i + 1) * H_ + n) * H_ + k]);
    } else if (idx < W1N + W2N + 5 * 65536) {
        int t = idx - (W1N + W2N);
        int g = t >> 16, e = t & 65535;
        const float* src = (g == 0) ? whr : (g == 1) ? whi : (g == 2) ? whh
                          : (g == 3) ? wo1 : wo2;
        gruw[t] = f2bf(src[e]);
    }
}

// U/V per node. U half gets b1 pre-folded.
// UV[(row*3+ty)*512 + half*256 + c]; grid: 25 m-tiles x 6 (ty,half), 4 waves.
__global__ __launch_bounds__(256) void uv_kernel(
        const unsigned short* __restrict__ hb, const unsigned short* __restrict__ w1s,
        const float* __restrict__ b1, float* __restrict__ UV) {
    int mm = blockIdx.x / 6;
    int tyh = blockIdx.x % 6;
    int ty = tyh >> 1, half = tyh & 1;
    int lane = threadIdx.x & 63, wid = threadIdx.x >> 6;
    int col = lane & 15, q = lane >> 4;
    const bf16x8* w1f = (const bf16x8*)w1s;

    f32x4 acc[4];
    #pragma unroll
    for (int u = 0; u < 4; ++u) acc[u] = (f32x4){0.f, 0.f, 0.f, 0.f};
    #pragma unroll
    for (int kt = 0; kt < 8; ++kt) {
        bf16x8 a = *(const bf16x8*)&hb[(size_t)(mm * 16 + col) * H_ + kt * 32 + q * 8];
        #pragma unroll
        for (int u = 0; u < 4; ++u) {
            bf16x8 w = w1f[(size_t)((ty * 16 + wid * 4 + u) * 16 + half * 8 + kt) * 64 + lane];
            acc[u] = __builtin_amdgcn_mfma_f32_16x16x32_bf16(a, w, acc[u], 0, 0, 0);
        }
    }
    #pragma unroll
    for (int u = 0; u < 4; ++u) {
        float bias = (half == 0) ? b1[(ty + 1) * H_ + (wid * 4 + u) * 16 + col] : 0.0f;
        #pragma unroll
        for (int r = 0; r < 4; ++r)
            UV[((size_t)(mm * 16 + q * 4 + r) * 3 + ty) * 512 + half * 256 +
               (wid * 4 + u) * 16 + col] = acc[u][r] + bias;
    }
}

// Fused m1-build + GEMM2 + sender-reduction. Block = (ty, b, recv r).
// Senders = ALL 50 nodes (rel[s==r] = 0). m1 staged in A-fragment order in LDS.
__global__ __launch_bounds__(256) void msgagg_kernel(
        const float* __restrict__ UV, const float* __restrict__ edges,
        const unsigned short* __restrict__ w2s,
        const float* __restrict__ b2, float* __restrict__ aggP, int t) {
    __shared__ unsigned short m1F[32 * 512];   // 32 frags x 1 KB, A-frag order
    __shared__ float relS[64];

    int ty = blockIdx.x / 400;
    int rem = blockIdx.x - ty * 400;
    int b = rem / 50;
    int r = rem - b * 50;
    int tid = threadIdx.x;
    int lane = tid & 63, wid = tid >> 6;
    int col = lane & 15, q = lane >> 4;

    if (tid < 64) {
        float v = 0.0f;
        if (tid < 50 && tid != r) {
            int e = tid * 49 + (r > tid ? r - 1 : r);
            v = edges[(((size_t)b * T_ + t) * E_ + e) * K_ + ty + 1];
        }
        relS[tid] = v;
    }

    // stage m1 frags: wave wid = m-tile; lane owns row = wid*16+col, cols q*8 + kt*32 + j
    {
        int row = wid * 16 + col;            // sender s (0..63; >=50 pad)
        int sv = row < N_ ? row : N_ - 1;
        float fl = (row < N_) ? 1.0f : 0.0f;
        const float* Vrow = &UV[((size_t)(b * N_ + sv) * 3 + ty) * 512 + 256 + q * 8];
        const float* Urow = &UV[((size_t)(b * N_ + r) * 3 + ty) * 512 + q * 8];
        #pragma unroll
        for (int kt = 0; kt < 8; ++kt) {
            float4 v0 = *(const float4*)(Vrow + kt * 32);
            float4 v1 = *(const float4*)(Vrow + kt * 32 + 4);
            float4 u0 = *(const float4*)(Urow + kt * 32);
            float4 u1 = *(const float4*)(Urow + kt * 32 + 4);
            float m0 = tanh_fast(u0.x + v0.x) * fl;
            float m1 = tanh_fast(u0.y + v0.y) * fl;
            float m2 = tanh_fast(u0.z + v0.z) * fl;
            float m3 = tanh_fast(u0.w + v0.w) * fl;
            float m4 = tanh_fast(u1.x + v1.x) * fl;
            float m5 = tanh_fast(u1.y + v1.y) * fl;
            float m6 = tanh_fast(u1.z + v1.z) * fl;
            float m7 = tanh_fast(u1.w + v1.w) * fl;
            uint4 pk;
            pk.x = pk2(m0, m1); pk.y = pk2(m2, m3);
            pk.z = pk2(m4, m5); pk.w = pk2(m6, m7);
            *(uint4*)&m1F[(wid * 8 + kt) * 512 + lane * 8] = pk;
        }
    }
    __syncthreads();

    const bf16x8* w2f = (const bf16x8*)w2s;
    f32x4 acc[4][4];
    #pragma unroll
    for (int mt = 0; mt < 4; ++mt)
        #pragma unroll
        for (int u = 0; u < 4; ++u) acc[mt][u] = (f32x4){0.f, 0.f, 0.f, 0.f};

    #pragma unroll
    for (int kt = 0; kt < 8; ++kt) {
        bf16x8 a0 = *(const bf16x8*)&m1F[(0 * 8 + kt) * 512 + lane * 8];
        bf16x8 a1 = *(const bf16x8*)&m1F[(1 * 8 + kt) * 512 + lane * 8];
        bf16x8 a2 = *(const bf16x8*)&m1F[(2 * 8 + kt) * 512 + lane * 8];
        bf16x8 a3 = *(const bf16x8*)&m1F[(3 * 8 + kt) * 512 + lane * 8];
        #pragma unroll
        for (int u = 0; u < 4; ++u) {
            bf16x8 w = w2f[(size_t)((ty * 16 + wid * 4 + u) * 8 + kt) * 64 + lane];
            acc[0][u] = __builtin_amdgcn_mfma_f32_16x16x32_bf16(a0, w, acc[0][u], 0, 0, 0);
            acc[1][u] = __builtin_amdgcn_mfma_f32_16x16x32_bf16(a1, w, acc[1][u], 0, 0, 0);
            acc[2][u] = __builtin_amdgcn_mfma_f32_16x16x32_bf16(a2, w, acc[2][u], 0, 0, 0);
            acc[3][u] = __builtin_amdgcn_mfma_f32_16x16x32_bf16(a3, w, acc[3][u], 0, 0, 0);
        }
    }
    #pragma unroll
    for (int u = 0; u < 4; ++u) {
        float bias = b2[(ty + 1) * H_ + (wid * 4 + u) * 16 + col];
        float sum = 0.0f;
        #pragma unroll
        for (int mt = 0; mt < 4; ++mt)
            #pragma unroll
            for (int rg = 0; rg < 4; ++rg) {
                int row = mt * 16 + q * 4 + rg;
                sum += tanh_fast(acc[mt][u][rg] + bias) * relS[row];
            }
        sum += __shfl_xor(sum, 16);
        sum += __shfl_xor(sum, 32);
        if (lane < 16)
            aggP[(size_t)ty * (B_ * N_ * H_) + (size_t)(b * N_ + r) * H_ +
                 (wid * 4 + u) * 16 + col] = sum * (1.0f / 3.0f);
    }
}

// GRU gate update + output MLP. 4 batch rows per block, bf16 weights.
__global__ __launch_bounds__(256) void gru_kernel(
        const float* __restrict__ inputs, const float* __restrict__ aggP,
        float* __restrict__ hidden, unsigned short* __restrict__ hidden_bf,
        const unsigned short* __restrict__ gruw,
        const float* __restrict__ w_ir, const float* __restrict__ b_ir,
        const float* __restrict__ w_ii, const float* __restrict__ b_ii,
        const float* __restrict__ w_in, const float* __restrict__ b_in,
        const float* __restrict__ b_o1, const float* __restrict__ b_o2,
        const float* __restrict__ w_o3, const float* __restrict__ b_o3,
        float* __restrict__ out, int t) {
    __shared__ float aggL[4][256];
    __shared__ float hnL[4][256];
    __shared__ float p1L[4][256];
    __shared__ float p2L[4][256];
    __shared__ float insL[4][8];

    int n = blockIdx.x >> 1;
    int bg = blockIdx.x & 1;
    int h = threadIdx.x;

    const unsigned short* whr = gruw;
    const unsigned short* whi = gruw + 65536;
    const unsigned short* whh = gruw + 2 * 65536;
    const unsigned short* wo1 = gruw + 3 * 65536;
    const unsigned short* wo2 = gruw + 4 * 65536;

    const float* src = (t == 0) ? inputs : out;
    int tt = (t == 0) ? 0 : (t - 1);
    const int AP = B_ * N_ * H_;

    #pragma unroll
    for (int r = 0; r < 4; ++r) {
        int bb = bg * 4 + r;
        size_t idx = (size_t)(bb * N_ + n) * H_ + h;
        aggL[r][h] = (aggP[idx] + aggP[AP + idx] + aggP[2 * AP + idx]) * (1.0f / 49.0f);
    }
    if (h < 24) {
        int r = h / 6, c = h % 6;
        int bb = bg * 4 + r;
        insL[r][c] = src[(((size_t)bb * T_ + tt) * N_ + n) * IN_ + c];
    }
    __syncthreads();

    float accR[4] = {0, 0, 0, 0}, accI[4] = {0, 0, 0, 0}, accN[4] = {0, 0, 0, 0};
    for (int k = 0; k < 256; k += 8) {
        uint4 uhr = *(const uint4*)&whr[h * 256 + k];
        uint4 uhi = *(const uint4*)&whi[h * 256 + k];
        uint4 uhh = *(const uint4*)&whh[h * 256 + k];
        float wr[8], wi[8], wh[8];
        unpk8(uhr, wr); unpk8(uhi, wi); unpk8(uhh, wh);
        #pragma unroll
        for (int r = 0; r < 4; ++r) {
            #pragma unroll
            for (int j = 0; j < 8; ++j) {
                float a = aggL[r][k + j];
                accR[r] += wr[j] * a;
                accI[r] += wi[j] * a;
                accN[r] += wh[j] * a;
            }
        }
    }
    float bir = b_ir[h], bii = b_ii[h], bin_ = b_in[h];
    #pragma unroll
    for (int r = 0; r < 4; ++r) {
        int bb = bg * 4 + r;
        float xr = bir, xi = bii, xn = bin_;
        #pragma unroll
        for (int c = 0; c < 6; ++c) {
            float iv = insL[r][c];
            xr += w_ir[h * 6 + c] * iv;
            xi += w_ii[h * 6 + c] * iv;
            xn += w_in[h * 6 + c] * iv;
        }
        float rg = sigmoid_fast(xr + accR[r]);
        float ig = sigmoid_fast(xi + accI[r]);
        float nn = tanh_fast(xn + rg * accN[r]);
        size_t hoff = (size_t)(bb * N_ + n) * H_ + h;
        float hold = hidden[hoff];
        float hnew = (1.0f - ig) * nn + ig * hold;
        hidden[hoff] = hnew;
        hidden_bf[hoff] = f2bf(hnew);
        hnL[r][h] = hnew;
    }
    __syncthreads();
    {
        float bo = b_o1[h];
        float p1a[4] = {bo, bo, bo, bo};
        for (int k = 0; k < 256; k += 8) {
            uint4 uw = *(const uint4*)&wo1[h * 256 + k];
            float w[8];
            unpk8(uw, w);
            #pragma unroll
            for (int r = 0; r < 4; ++r)
                #pragma unroll
                for (int j = 0; j < 8; ++j) p1a[r] += w[j] * hnL[r][k + j];
        }
        #pragma unroll
        for (int r = 0; r < 4; ++r) p1L[r][h] = fmaxf(p1a[r], 0.0f);
    }
    __syncthreads();
    {
        float bo = b_o2[h];
        float p2a[4] = {bo, bo, bo, bo};
        for (int k = 0; k < 256; k += 8) {
            uint4 uw = *(const uint4*)&wo2[h * 256 + k];
            float w[8];
            unpk8(uw, w);
            #pragma unroll
            for (int r = 0; r < 4; ++r)
                #pragma unroll
                for (int j = 0; j < 8; ++j) p2a[r] += w[j] * p1L[r][k + j];
        }
        #pragma unroll
        for (int r = 0; r < 4; ++r) p2L[r][h] = fmaxf(p2a[r], 0.0f);
    }
    __syncthreads();
    if (h < 24) {
        int r = h / 6, c = h % 6;
        int bb = bg * 4 + r;
        float acc = b_o3[c];
        for (int k = 0; k < 256; ++k) acc += w_o3[c * 256 + k] * p2L[r][k];
        out[(((size_t)bb * T_ + t) * N_ + n) * IN_ + c] = insL[r][c] + acc;
    }
}

extern "C" void kernel_launch(void* const* d_in, const int* in_sizes, int n_in,
                              void* d_out, int out_size, void* d_ws, size_t ws_size,
                              hipStream_t stream) {
    const float* inputs = (const float*)d_in[0];
    const float* edges  = (const float*)d_in[1];
    const float* msg_w1 = (const float*)d_in[2];
    const float* msg_b1 = (const float*)d_in[3];
    const float* msg_w2 = (const float*)d_in[4];
    const float* msg_b2 = (const float*)d_in[5];
    const float* w_hr = (const float*)d_in[6];
    const float* w_hi = (const float*)d_in[7];
    const float* w_hh = (const float*)d_in[8];
    const float* w_ir = (const float*)d_in[9];
    const float* b_ir = (const float*)d_in[10];
    const float* w_ii = (const float*)d_in[11];
    const float* b_ii = (const float*)d_in[12];
    const float* w_in = (const float*)d_in[13];
    const float* b_in = (const float*)d_in[14];
    const float* w_o1 = (const float*)d_in[15];
    const float* b_o1 = (const float*)d_in[16];
    const float* w_o2 = (const float*)d_in[17];
    const float* b_o2 = (const float*)d_in[18];
    const float* w_o3 = (const float*)d_in[19];
    const float* b_o3 = (const float*)d_in[20];
    float* out = (float*)d_out;

    char* ws = (char*)d_ws;
    float* hidden            = (float*)(ws);                       // 409,600 B
    unsigned short* hidden_bf= (unsigned short*)(ws + 409600);     // 204,800 B
    float* UV                = (float*)(ws + 614400);              // 2,457,600 B
    float* aggP              = (float*)(ws + 3072000);             // 1,228,800 B
    unsigned short* w1s      = (unsigned short*)(ws + 4300800);    // 786,432 B
    unsigned short* w2s      = (unsigned short*)(ws + 5087232);    // 393,216 B
    unsigned short* gruw     = (unsigned short*)(ws + 5480448);    // 655,360 B

    zero_ws<<<dim3(600), dim3(256), 0, stream>>>((unsigned int*)ws, 153600);
    swizzle_weights<<<dim3(3584), dim3(256), 0, stream>>>(
        msg_w1, msg_w2, w_hr, w_hi, w_hh, w_o1, w_o2, w1s, w2s, gruw);

    for (int t = 0; t < T_; ++t) {
        uv_kernel<<<dim3(150), dim3(256), 0, stream>>>(hidden_bf, w1s, msg_b1, UV);
        msgagg_kernel<<<dim3(1200), dim3(256), 0, stream>>>(
            UV, edges, w2s, msg_b2, aggP, t);
        gru_kernel<<<dim3(100), dim3(256), 0, stream>>>(
            inputs, aggP, hidden, hidden_bf, gruw,
            w_ir, b_ir, w_ii, b_ii, w_in, b_in, b_o1, b_o2, w_o3, b_o3, out, t);
    }
}

// Round 4
// 752.126 us; speedup vs baseline: 3.4853x; 1.1449x over previous
//
#include <hip/hip_runtime.h>
#include <hip/hip_bf16.h>
#include <stdint.h>

#define B_ 8
#define T_ 10
#define N_ 50
#define IN_ 6
#define H_ 256
#define K_ 4
#define E_ 2450

typedef __attribute__((ext_vector_type(8))) __bf16 bf16x8;
typedef __attribute__((ext_vector_type(4))) float f32x4;

__device__ __forceinline__ unsigned short f2bf(float x) {
    unsigned int u = __float_as_uint(x);
    u = (u + 0x7fffu + ((u >> 16) & 1u)) >> 16;   // RNE
    return (unsigned short)u;
}
__device__ __forceinline__ unsigned pk2(float a, float b) {
    return (unsigned)f2bf(a) | ((unsigned)f2bf(b) << 16);
}
__device__ __forceinline__ float rcp_fast(float x) { return __builtin_amdgcn_rcpf(x); }
__device__ __forceinline__ float tanh_fast(float x) {
    float e = __expf(2.0f * x);
    return 1.0f - 2.0f * rcp_fast(e + 1.0f);
}
__device__ __forceinline__ float sigmoid_fast(float x) {
    return rcp_fast(1.0f + __expf(-x));
}
__device__ __forceinline__ void unpk8(uint4 u, float* w) {
    w[0] = __uint_as_float(u.x << 16); w[1] = __uint_as_float(u.x & 0xffff0000u);
    w[2] = __uint_as_float(u.y << 16); w[3] = __uint_as_float(u.y & 0xffff0000u);
    w[4] = __uint_as_float(u.z << 16); w[5] = __uint_as_float(u.z & 0xffff0000u);
    w[6] = __uint_as_float(u.w << 16); w[7] = __uint_as_float(u.w & 0xffff0000u);
}

// Swizzle msg weights into MFMA B-frag order + GRU weights to bf16 + zero hidden.
// Index layout: [0,W1N) w1s | [W1N,+W2N) w2s | [+, +327680) gruw | [+, +153600) zero words
__global__ __launch_bounds__(256) void swizzle_weights(
        const float* __restrict__ w1, const float* __restrict__ w2,
        const float* __restrict__ whr, const float* __restrict__ whi,
        const float* __restrict__ whh, const float* __restrict__ wo1,
        const float* __restrict__ wo2,
        unsigned short* __restrict__ w1s, unsigned short* __restrict__ w2s,
        unsigned short* __restrict__ gruw, unsigned int* __restrict__ zero_region) {
    const int W1N = 3 * 16 * 16 * 64 * 8;   // 393216
    const int W2N = 3 * 16 * 8 * 64 * 8;    // 196608
    int idx = blockIdx.x * 256 + threadIdx.x;
    if (idx < W1N) {
        int j = idx & 7, L = (idx >> 3) & 63, kt = (idx >> 9) & 15;
        int nt = (idx >> 13) & 15, i = idx >> 17;
        int n = nt * 16 + (L & 15);
        int k = kt * 32 + ((L >> 4) << 3) + j;
        w1s[idx] = f2bf(w1[((size_t)(i + 1) * H_ + n) * (2 * H_) + k]);
    } else if (idx < W1N + W2N) {
        int t = idx - W1N;
        int j = t & 7, L = (t >> 3) & 63, kt = (t >> 9) & 7;
        int nt = (t >> 12) & 15, i = t >> 16;
        int n = nt * 16 + (L & 15);
        int k = kt * 32 + ((L >> 4) << 3) + j;
        w2s[t] = f2bf(w2[((size_t)(i + 1) * H_ + n) * H_ + k]);
    } else if (idx < W1N + W2N + 5 * 65536) {
        int t = idx - (W1N + W2N);
        int g = t >> 16, e = t & 65535;
        const float* src = (g == 0) ? whr : (g == 1) ? whi : (g == 2) ? whh
                          : (g == 3) ? wo1 : wo2;
        gruw[t] = f2bf(src[e]);
    } else {
        int t = idx - (W1N + W2N + 5 * 65536);
        if (t < 153600) zero_region[t] = 0u;
    }
}

// U/V per node. U half gets b1 pre-folded.
__global__ __launch_bounds__(256) void uv_kernel(
        const unsigned short* __restrict__ hb, const unsigned short* __restrict__ w1s,
        const float* __restrict__ b1, float* __restrict__ UV) {
    int mm = blockIdx.x / 6;
    int tyh = blockIdx.x % 6;
    int ty = tyh >> 1, half = tyh & 1;
    int lane = threadIdx.x & 63, wid = threadIdx.x >> 6;
    int col = lane & 15, q = lane >> 4;
    const bf16x8* w1f = (const bf16x8*)w1s;

    f32x4 acc[4];
    #pragma unroll
    for (int u = 0; u < 4; ++u) acc[u] = (f32x4){0.f, 0.f, 0.f, 0.f};
    #pragma unroll
    for (int kt = 0; kt < 8; ++kt) {
        bf16x8 a = *(const bf16x8*)&hb[(size_t)(mm * 16 + col) * H_ + kt * 32 + q * 8];
        #pragma unroll
        for (int u = 0; u < 4; ++u) {
            bf16x8 w = w1f[(size_t)((ty * 16 + wid * 4 + u) * 16 + half * 8 + kt) * 64 + lane];
            acc[u] = __builtin_amdgcn_mfma_f32_16x16x32_bf16(a, w, acc[u], 0, 0, 0);
        }
    }
    #pragma unroll
    for (int u = 0; u < 4; ++u) {
        float bias = (half == 0) ? b1[(ty + 1) * H_ + (wid * 4 + u) * 16 + col] : 0.0f;
        #pragma unroll
        for (int r = 0; r < 4; ++r)
            UV[((size_t)(mm * 16 + q * 4 + r) * 3 + ty) * 512 + half * 256 +
               (wid * 4 + u) * 16 + col] = acc[u][r] + bias;
    }
}

// Fused m1-build + GEMM2 + sender-reduction. Block = (ty, b, recv r).
__global__ __launch_bounds__(256, 4) void msgagg_kernel(
        const float* __restrict__ UV, const float* __restrict__ edges,
        const unsigned short* __restrict__ w2s,
        const float* __restrict__ b2, float* __restrict__ aggP, int t) {
    __shared__ unsigned short m1F[32 * 512];   // 32 frags x 1 KB, A-frag order
    __shared__ float relS[64];

    int ty = blockIdx.x / 400;
    int rem = blockIdx.x - ty * 400;
    int b = rem / 50;
    int r = rem - b * 50;
    int tid = threadIdx.x;
    int lane = tid & 63, wid = tid >> 6;
    int col = lane & 15, q = lane >> 4;

    if (tid < 64) {
        float v = 0.0f;
        if (tid < 50 && tid != r) {
            int e = tid * 49 + (r > tid ? r - 1 : r);
            v = edges[(((size_t)b * T_ + t) * E_ + e) * K_ + ty + 1];
        }
        relS[tid] = v;
    }

    {
        int row = wid * 16 + col;            // sender s (0..63; >=50 pad)
        int sv = row < N_ ? row : N_ - 1;
        float fl = (row < N_) ? 1.0f : 0.0f;
        const float* Vrow = &UV[((size_t)(b * N_ + sv) * 3 + ty) * 512 + 256 + q * 8];
        const float* Urow = &UV[((size_t)(b * N_ + r) * 3 + ty) * 512 + q * 8];
        #pragma unroll
        for (int kt = 0; kt < 8; ++kt) {
            float4 v0 = *(const float4*)(Vrow + kt * 32);
            float4 v1 = *(const float4*)(Vrow + kt * 32 + 4);
            float4 u0 = *(const float4*)(Urow + kt * 32);
            float4 u1 = *(const float4*)(Urow + kt * 32 + 4);
            float m0 = tanh_fast(u0.x + v0.x) * fl;
            float m1 = tanh_fast(u0.y + v0.y) * fl;
            float m2 = tanh_fast(u0.z + v0.z) * fl;
            float m3 = tanh_fast(u0.w + v0.w) * fl;
            float m4 = tanh_fast(u1.x + v1.x) * fl;
            float m5 = tanh_fast(u1.y + v1.y) * fl;
            float m6 = tanh_fast(u1.z + v1.z) * fl;
            float m7 = tanh_fast(u1.w + v1.w) * fl;
            uint4 pk;
            pk.x = pk2(m0, m1); pk.y = pk2(m2, m3);
            pk.z = pk2(m4, m5); pk.w = pk2(m6, m7);
            *(uint4*)&m1F[(wid * 8 + kt) * 512 + lane * 8] = pk;
        }
    }
    __syncthreads();

    const bf16x8* w2f = (const bf16x8*)w2s;
    f32x4 acc[4][4];
    #pragma unroll
    for (int mt = 0; mt < 4; ++mt)
        #pragma unroll
        for (int u = 0; u < 4; ++u) acc[mt][u] = (f32x4){0.f, 0.f, 0.f, 0.f};

    #pragma unroll
    for (int kt = 0; kt < 8; ++kt) {
        bf16x8 a0 = *(const bf16x8*)&m1F[(0 * 8 + kt) * 512 + lane * 8];
        bf16x8 a1 = *(const bf16x8*)&m1F[(1 * 8 + kt) * 512 + lane * 8];
        bf16x8 a2 = *(const bf16x8*)&m1F[(2 * 8 + kt) * 512 + lane * 8];
        bf16x8 a3 = *(const bf16x8*)&m1F[(3 * 8 + kt) * 512 + lane * 8];
        #pragma unroll
        for (int u = 0; u < 4; ++u) {
            bf16x8 w = w2f[(size_t)((ty * 16 + wid * 4 + u) * 8 + kt) * 64 + lane];
            acc[0][u] = __builtin_amdgcn_mfma_f32_16x16x32_bf16(a0, w, acc[0][u], 0, 0, 0);
            acc[1][u] = __builtin_amdgcn_mfma_f32_16x16x32_bf16(a1, w, acc[1][u], 0, 0, 0);
            acc[2][u] = __builtin_amdgcn_mfma_f32_16x16x32_bf16(a2, w, acc[2][u], 0, 0, 0);
            acc[3][u] = __builtin_amdgcn_mfma_f32_16x16x32_bf16(a3, w, acc[3][u], 0, 0, 0);
        }
    }
    #pragma unroll
    for (int u = 0; u < 4; ++u) {
        float bias = b2[(ty + 1) * H_ + (wid * 4 + u) * 16 + col];
        float sum = 0.0f;
        #pragma unroll
        for (int mt = 0; mt < 4; ++mt)
            #pragma unroll
            for (int rg = 0; rg < 4; ++rg) {
                int row = mt * 16 + q * 4 + rg;
                sum += tanh_fast(acc[mt][u][rg] + bias) * relS[row];
            }
        sum += __shfl_xor(sum, 16);
        sum += __shfl_xor(sum, 32);
        if (lane < 16)
            aggP[(size_t)ty * (B_ * N_ * H_) + (size_t)(b * N_ + r) * H_ +
                 (wid * 4 + u) * 16 + col] = sum * (1.0f / 3.0f);
    }
}

// GRU gate update + output MLP. 2 batch rows per block (200 blocks), bf16 weights.
__global__ __launch_bounds__(256) void gru_kernel(
        const float* __restrict__ inputs, const float* __restrict__ aggP,
        float* __restrict__ hidden, unsigned short* __restrict__ hidden_bf,
        const unsigned short* __restrict__ gruw,
        const float* __restrict__ w_ir, const float* __restrict__ b_ir,
        const float* __restrict__ w_ii, const float* __restrict__ b_ii,
        const float* __restrict__ w_in, const float* __restrict__ b_in,
        const float* __restrict__ b_o1, const float* __restrict__ b_o2,
        const float* __restrict__ w_o3, const float* __restrict__ b_o3,
        float* __restrict__ out, int t) {
    __shared__ float aggL[2][256];
    __shared__ float hnL[2][256];
    __shared__ float p1L[2][256];
    __shared__ float p2L[2][256];
    __shared__ float insL[2][8];

    int n = blockIdx.x >> 2;
    int bg = blockIdx.x & 3;
    int h = threadIdx.x;

    const unsigned short* whr = gruw;
    const unsigned short* whi = gruw + 65536;
    const unsigned short* whh = gruw + 2 * 65536;
    const unsigned short* wo1 = gruw + 3 * 65536;
    const unsigned short* wo2 = gruw + 4 * 65536;

    const float* src = (t == 0) ? inputs : out;
    int tt = (t == 0) ? 0 : (t - 1);
    const int AP = B_ * N_ * H_;

    #pragma unroll
    for (int r = 0; r < 2; ++r) {
        int bb = bg * 2 + r;
        size_t idx = (size_t)(bb * N_ + n) * H_ + h;
        aggL[r][h] = (aggP[idx] + aggP[AP + idx] + aggP[2 * AP + idx]) * (1.0f / 49.0f);
    }
    if (h < 12) {
        int r = h / 6, c = h % 6;
        int bb = bg * 2 + r;
        insL[r][c] = src[(((size_t)bb * T_ + tt) * N_ + n) * IN_ + c];
    }
    __syncthreads();

    float accR[2] = {0, 0}, accI[2] = {0, 0}, accN[2] = {0, 0};
    for (int k = 0; k < 256; k += 8) {
        uint4 uhr = *(const uint4*)&whr[h * 256 + k];
        uint4 uhi = *(const uint4*)&whi[h * 256 + k];
        uint4 uhh = *(const uint4*)&whh[h * 256 + k];
        float wr[8], wi[8], wh[8];
        unpk8(uhr, wr); unpk8(uhi, wi); unpk8(uhh, wh);
        #pragma unroll
        for (int r = 0; r < 2; ++r) {
            #pragma unroll
            for (int j = 0; j < 8; ++j) {
                float a = aggL[r][k + j];
                accR[r] += wr[j] * a;
                accI[r] += wi[j] * a;
                accN[r] += wh[j] * a;
            }
        }
    }
    float bir = b_ir[h], bii = b_ii[h], bin_ = b_in[h];
    #pragma unroll
    for (int r = 0; r < 2; ++r) {
        int bb = bg * 2 + r;
        float xr = bir, xi = bii, xn = bin_;
        #pragma unroll
        for (int c = 0; c < 6; ++c) {
            float iv = insL[r][c];
            xr += w_ir[h * 6 + c] * iv;
            xi += w_ii[h * 6 + c] * iv;
            xn += w_in[h * 6 + c] * iv;
        }
        float rg = sigmoid_fast(xr + accR[r]);
        float ig = sigmoid_fast(xi + accI[r]);
        float nn = tanh_fast(xn + rg * accN[r]);
        size_t hoff = (size_t)(bb * N_ + n) * H_ + h;
        float hold = hidden[hoff];
        float hnew = (1.0f - ig) * nn + ig * hold;
        hidden[hoff] = hnew;
        hidden_bf[hoff] = f2bf(hnew);
        hnL[r][h] = hnew;
    }
    __syncthreads();
    {
        float bo = b_o1[h];
        float p1a[2] = {bo, bo};
        for (int k = 0; k < 256; k += 8) {
            uint4 uw = *(const uint4*)&wo1[h * 256 + k];
            float w[8];
            unpk8(uw, w);
            #pragma unroll
            for (int r = 0; r < 2; ++r)
                #pragma unroll
                for (int j = 0; j < 8; ++j) p1a[r] += w[j] * hnL[r][k + j];
        }
        #pragma unroll
        for (int r = 0; r < 2; ++r) p1L[r][h] = fmaxf(p1a[r], 0.0f);
    }
    __syncthreads();
    {
        float bo = b_o2[h];
        float p2a[2] = {bo, bo};
        for (int k = 0; k < 256; k += 8) {
            uint4 uw = *(const uint4*)&wo2[h * 256 + k];
            float w[8];
            unpk8(uw, w);
            #pragma unroll
            for (int r = 0; r < 2; ++r)
                #pragma unroll
                for (int j = 0; j < 8; ++j) p2a[r] += w[j] * p1L[r][k + j];
        }
        #pragma unroll
        for (int r = 0; r < 2; ++r) p2L[r][h] = fmaxf(p2a[r], 0.0f);
    }
    __syncthreads();
    if (h < 12) {
        int r = h / 6, c = h % 6;
        int bb = bg * 2 + r;
        float acc = b_o3[c];
        for (int k = 0; k < 256; ++k) acc += w_o3[c * 256 + k] * p2L[r][k];
        out[(((size_t)bb * T_ + t) * N_ + n) * IN_ + c] = insL[r][c] + acc;
    }
}

extern "C" void kernel_launch(void* const* d_in, const int* in_sizes, int n_in,
                              void* d_out, int out_size, void* d_ws, size_t ws_size,
                              hipStream_t stream) {
    const float* inputs = (const float*)d_in[0];
    const float* edges  = (const float*)d_in[1];
    const float* msg_w1 = (const float*)d_in[2];
    const float* msg_b1 = (const float*)d_in[3];
    const float* msg_w2 = (const float*)d_in[4];
    const float* msg_b2 = (const float*)d_in[5];
    const float* w_hr = (const float*)d_in[6];
    const float* w_hi = (const float*)d_in[7];
    const float* w_hh = (const float*)d_in[8];
    const float* w_ir = (const float*)d_in[9];
    const float* b_ir = (const float*)d_in[10];
    const float* w_ii = (const float*)d_in[11];
    const float* b_ii = (const float*)d_in[12];
    const float* w_in = (const float*)d_in[13];
    const float* b_in = (const float*)d_in[14];
    const float* w_o1 = (const float*)d_in[15];
    const float* b_o1 = (const float*)d_in[16];
    const float* w_o2 = (const float*)d_in[17];
    const float* b_o2 = (const float*)d_in[18];
    const float* w_o3 = (const float*)d_in[19];
    const float* b_o3 = (const float*)d_in[20];
    float* out = (float*)d_out;

    char* ws = (char*)d_ws;
    float* hidden            = (float*)(ws);                       // 409,600 B
    unsigned short* hidden_bf= (unsigned short*)(ws + 409600);     // 204,800 B
    float* UV                = (float*)(ws + 614400);              // 2,457,600 B
    float* aggP              = (float*)(ws + 3072000);             // 1,228,800 B
    unsigned short* w1s      = (unsigned short*)(ws + 4300800);    // 786,432 B
    unsigned short* w2s      = (unsigned short*)(ws + 5087232);    // 393,216 B
    unsigned short* gruw     = (unsigned short*)(ws + 5480448);    // 655,360 B

    // one setup kernel: swizzle weights + zero hidden/hidden_bf (153600 words)
    swizzle_weights<<<dim3(4184), dim3(256), 0, stream>>>(
        msg_w1, msg_w2, w_hr, w_hi, w_hh, w_o1, w_o2, w1s, w2s, gruw,
        (unsigned int*)ws);

    for (int t = 0; t < T_; ++t) {
        uv_kernel<<<dim3(150), dim3(256), 0, stream>>>(hidden_bf, w1s, msg_b1, UV);
        msgagg_kernel<<<dim3(1200), dim3(256), 0, stream>>>(
            UV, edges, w2s, msg_b2, aggP, t);
        gru_kernel<<<dim3(200), dim3(256), 0, stream>>>(
            inputs, aggP, hidden, hidden_bf, gruw,
            w_ir, b_ir, w_ii, b_ii, w_in, b_in, b_o1, b_o2, w_o3, b_o3, out, t);
    }
}

// Round 5
// 648.985 us; speedup vs baseline: 4.0392x; 1.1589x over previous
//
#include <hip/hip_runtime.h>
#include <hip/hip_bf16.h>
#include <stdint.h>

#define B_ 8
#define T_ 10
#define N_ 50
#define IN_ 6
#define H_ 256
#define K_ 4
#define E_ 2450
#define ROWS 400           // B_*N_
#define AP 102400          // ROWS*H_

typedef __attribute__((ext_vector_type(8))) __bf16 bf16x8;
typedef __attribute__((ext_vector_type(4))) float f32x4;

__device__ __forceinline__ unsigned short f2bf(float x) {
    unsigned int u = __float_as_uint(x);
    u = (u + 0x7fffu + ((u >> 16) & 1u)) >> 16;   // RNE
    return (unsigned short)u;
}
__device__ __forceinline__ unsigned pk2(float a, float b) {
    return (unsigned)f2bf(a) | ((unsigned)f2bf(b) << 16);
}
__device__ __forceinline__ float rcp_fast(float x) { return __builtin_amdgcn_rcpf(x); }
__device__ __forceinline__ float tanh_fast(float x) {
    float e = __expf(2.0f * x);
    return 1.0f - 2.0f * rcp_fast(e + 1.0f);
}
__device__ __forceinline__ float sigmoid_fast(float x) {
    return rcp_fast(1.0f + __expf(-x));
}
__device__ __forceinline__ void unpk8(uint4 u, float* w) {
    w[0] = __uint_as_float(u.x << 16); w[1] = __uint_as_float(u.x & 0xffff0000u);
    w[2] = __uint_as_float(u.y << 16); w[3] = __uint_as_float(u.y & 0xffff0000u);
    w[4] = __uint_as_float(u.z << 16); w[5] = __uint_as_float(u.z & 0xffff0000u);
    w[6] = __uint_as_float(u.w << 16); w[7] = __uint_as_float(u.w & 0xffff0000u);
}

// Swizzle: w1s | w2s | gws (whr/whi/whh B-frag) | gruw (wo1,wo2 plain bf16) | zero hidden.
__global__ __launch_bounds__(256) void swizzle_weights(
        const float* __restrict__ w1, const float* __restrict__ w2,
        const float* __restrict__ whr, const float* __restrict__ whi,
        const float* __restrict__ whh, const float* __restrict__ wo1,
        const float* __restrict__ wo2,
        unsigned short* __restrict__ w1s, unsigned short* __restrict__ w2s,
        unsigned short* __restrict__ gws, unsigned short* __restrict__ gruw,
        unsigned int* __restrict__ zero_region) {
    const int W1N = 3 * 16 * 16 * 64 * 8;   // 393216
    const int W2N = 3 * 16 * 8 * 64 * 8;    // 196608
    const int GWN = 3 * 65536;              // 196608
    const int WON = 2 * 65536;              // 131072
    int idx = blockIdx.x * 256 + threadIdx.x;
    if (idx < W1N) {
        int j = idx & 7, L = (idx >> 3) & 63, kt = (idx >> 9) & 15;
        int nt = (idx >> 13) & 15, i = idx >> 17;
        int n = nt * 16 + (L & 15);
        int k = kt * 32 + ((L >> 4) << 3) + j;
        w1s[idx] = f2bf(w1[((size_t)(i + 1) * H_ + n) * (2 * H_) + k]);
    } else if (idx < W1N + W2N) {
        int t = idx - W1N;
        int j = t & 7, L = (t >> 3) & 63, kt = (t >> 9) & 7;
        int nt = (t >> 12) & 15, i = t >> 16;
        int n = nt * 16 + (L & 15);
        int k = kt * 32 + ((L >> 4) << 3) + j;
        w2s[t] = f2bf(w2[((size_t)(i + 1) * H_ + n) * H_ + k]);
    } else if (idx < W1N + W2N + GWN) {
        int t = idx - (W1N + W2N);
        int j = t & 7, L = (t >> 3) & 63, kt = (t >> 9) & 7;
        int nt = (t >> 12) & 15, mat = t >> 16;
        int n = nt * 16 + (L & 15);
        int k = kt * 32 + ((L >> 4) << 3) + j;
        const float* src = (mat == 0) ? whr : (mat == 1) ? whi : whh;
        gws[t] = f2bf(src[(size_t)n * H_ + k]);
    } else if (idx < W1N + W2N + GWN + WON) {
        int t = idx - (W1N + W2N + GWN);
        int g = t >> 16, e = t & 65535;
        gruw[t] = f2bf(g == 0 ? wo1[e] : wo2[e]);
    } else {
        int t = idx - (W1N + W2N + GWN + WON);
        if (t < 153600) zero_region[t] = 0u;
    }
}

// U/V per node. U half gets b1 pre-folded.
__global__ __launch_bounds__(256) void uv_kernel(
        const unsigned short* __restrict__ hb, const unsigned short* __restrict__ w1s,
        const float* __restrict__ b1, float* __restrict__ UV) {
    int mm = blockIdx.x / 6;
    int tyh = blockIdx.x % 6;
    int ty = tyh >> 1, half = tyh & 1;
    int lane = threadIdx.x & 63, wid = threadIdx.x >> 6;
    int col = lane & 15, q = lane >> 4;
    const bf16x8* w1f = (const bf16x8*)w1s;

    f32x4 acc[4];
    #pragma unroll
    for (int u = 0; u < 4; ++u) acc[u] = (f32x4){0.f, 0.f, 0.f, 0.f};
    #pragma unroll
    for (int kt = 0; kt < 8; ++kt) {
        bf16x8 a = *(const bf16x8*)&hb[(size_t)(mm * 16 + col) * H_ + kt * 32 + q * 8];
        #pragma unroll
        for (int u = 0; u < 4; ++u) {
            bf16x8 w = w1f[(size_t)((ty * 16 + wid * 4 + u) * 16 + half * 8 + kt) * 64 + lane];
            acc[u] = __builtin_amdgcn_mfma_f32_16x16x32_bf16(a, w, acc[u], 0, 0, 0);
        }
    }
    #pragma unroll
    for (int u = 0; u < 4; ++u) {
        float bias = (half == 0) ? b1[(ty + 1) * H_ + (wid * 4 + u) * 16 + col] : 0.0f;
        #pragma unroll
        for (int r = 0; r < 4; ++r)
            UV[((size_t)(mm * 16 + q * 4 + r) * 3 + ty) * 512 + half * 256 +
               (wid * 4 + u) * 16 + col] = acc[u][r] + bias;
    }
}

// Fused m1-build + GEMM2 + sender-reduction. Block = (ty, b, recv r).
// NOTE: output scaled by 1/147 = (1/3 msg norm) * (1/49 agg norm).
__global__ __launch_bounds__(256, 4) void msgagg_kernel(
        const float* __restrict__ UV, const float* __restrict__ edges,
        const unsigned short* __restrict__ w2s,
        const float* __restrict__ b2, float* __restrict__ aggP, int t) {
    __shared__ unsigned short m1F[32 * 512];
    __shared__ float relS[64];

    int ty = blockIdx.x / 400;
    int rem = blockIdx.x - ty * 400;
    int b = rem / 50;
    int r = rem - b * 50;
    int tid = threadIdx.x;
    int lane = tid & 63, wid = tid >> 6;
    int col = lane & 15, q = lane >> 4;

    if (tid < 64) {
        float v = 0.0f;
        if (tid < 50 && tid != r) {
            int e = tid * 49 + (r > tid ? r - 1 : r);
            v = edges[(((size_t)b * T_ + t) * E_ + e) * K_ + ty + 1];
        }
        relS[tid] = v;
    }

    {
        int row = wid * 16 + col;
        int sv = row < N_ ? row : N_ - 1;
        float fl = (row < N_) ? 1.0f : 0.0f;
        const float* Vrow = &UV[((size_t)(b * N_ + sv) * 3 + ty) * 512 + 256 + q * 8];
        const float* Urow = &UV[((size_t)(b * N_ + r) * 3 + ty) * 512 + q * 8];
        #pragma unroll
        for (int kt = 0; kt < 8; ++kt) {
            float4 v0 = *(const float4*)(Vrow + kt * 32);
            float4 v1 = *(const float4*)(Vrow + kt * 32 + 4);
            float4 u0 = *(const float4*)(Urow + kt * 32);
            float4 u1 = *(const float4*)(Urow + kt * 32 + 4);
            float m0 = tanh_fast(u0.x + v0.x) * fl;
            float m1 = tanh_fast(u0.y + v0.y) * fl;
            float m2 = tanh_fast(u0.z + v0.z) * fl;
            float m3 = tanh_fast(u0.w + v0.w) * fl;
            float m4 = tanh_fast(u1.x + v1.x) * fl;
            float m5 = tanh_fast(u1.y + v1.y) * fl;
            float m6 = tanh_fast(u1.z + v1.z) * fl;
            float m7 = tanh_fast(u1.w + v1.w) * fl;
            uint4 pk;
            pk.x = pk2(m0, m1); pk.y = pk2(m2, m3);
            pk.z = pk2(m4, m5); pk.w = pk2(m6, m7);
            *(uint4*)&m1F[(wid * 8 + kt) * 512 + lane * 8] = pk;
        }
    }
    __syncthreads();

    const bf16x8* w2f = (const bf16x8*)w2s;
    f32x4 acc[4][4];
    #pragma unroll
    for (int mt = 0; mt < 4; ++mt)
        #pragma unroll
        for (int u = 0; u < 4; ++u) acc[mt][u] = (f32x4){0.f, 0.f, 0.f, 0.f};

    #pragma unroll
    for (int kt = 0; kt < 8; ++kt) {
        bf16x8 a0 = *(const bf16x8*)&m1F[(0 * 8 + kt) * 512 + lane * 8];
        bf16x8 a1 = *(const bf16x8*)&m1F[(1 * 8 + kt) * 512 + lane * 8];
        bf16x8 a2 = *(const bf16x8*)&m1F[(2 * 8 + kt) * 512 + lane * 8];
        bf16x8 a3 = *(const bf16x8*)&m1F[(3 * 8 + kt) * 512 + lane * 8];
        #pragma unroll
        for (int u = 0; u < 4; ++u) {
            bf16x8 w = w2f[(size_t)((ty * 16 + wid * 4 + u) * 8 + kt) * 64 + lane];
            acc[0][u] = __builtin_amdgcn_mfma_f32_16x16x32_bf16(a0, w, acc[0][u], 0, 0, 0);
            acc[1][u] = __builtin_amdgcn_mfma_f32_16x16x32_bf16(a1, w, acc[1][u], 0, 0, 0);
            acc[2][u] = __builtin_amdgcn_mfma_f32_16x16x32_bf16(a2, w, acc[2][u], 0, 0, 0);
            acc[3][u] = __builtin_amdgcn_mfma_f32_16x16x32_bf16(a3, w, acc[3][u], 0, 0, 0);
        }
    }
    #pragma unroll
    for (int u = 0; u < 4; ++u) {
        float bias = b2[(ty + 1) * H_ + (wid * 4 + u) * 16 + col];
        float sum = 0.0f;
        #pragma unroll
        for (int mt = 0; mt < 4; ++mt)
            #pragma unroll
            for (int rg = 0; rg < 4; ++rg) {
                int row = mt * 16 + q * 4 + rg;
                sum += tanh_fast(acc[mt][u][rg] + bias) * relS[row];
            }
        sum += __shfl_xor(sum, 16);
        sum += __shfl_xor(sum, 32);
        if (lane < 16)
            aggP[(size_t)ty * AP + (size_t)(b * N_ + r) * H_ +
                 (wid * 4 + u) * 16 + col] = sum * (1.0f / 147.0f);
    }
}

// Gates GEMM: G[mat][row][col] = agg[row] @ W[mat]^T, mat in {whr,whi,whh}.
// agg[row] = sum of 3 aggP partials (already /147-scaled).
// Grid: 25 m-tiles x 6 (mat, half). 4 waves; wave handles 2 n-tiles.
__global__ __launch_bounds__(256, 4) void gates_kernel(
        const float* __restrict__ aggP, const unsigned short* __restrict__ gws,
        float* __restrict__ G) {
    __shared__ unsigned short aF[8 * 512];

    int mt = blockIdx.x / 6;
    int g = blockIdx.x % 6;
    int mat = g >> 1, half = g & 1;
    int tid = threadIdx.x;
    int lane = tid & 63, wid = tid >> 6;
    int col = lane & 15, q = lane >> 4;

    #pragma unroll
    for (int s = 0; s < 2; ++s) {
        int slot = tid + s * 256;
        int kt = slot >> 6, L = slot & 63;
        int row = mt * 16 + (L & 15);
        int k0 = kt * 32 + ((L >> 4) << 3);
        const float* p = &aggP[(size_t)row * H_ + k0];
        float4 a0 = *(const float4*)(p);
        float4 a1 = *(const float4*)(p + 4);
        float4 b0 = *(const float4*)(p + AP);
        float4 b1 = *(const float4*)(p + AP + 4);
        float4 c0 = *(const float4*)(p + 2 * AP);
        float4 c1 = *(const float4*)(p + 2 * AP + 4);
        uint4 pk;
        pk.x = pk2(a0.x + b0.x + c0.x, a0.y + b0.y + c0.y);
        pk.y = pk2(a0.z + b0.z + c0.z, a0.w + b0.w + c0.w);
        pk.z = pk2(a1.x + b1.x + c1.x, a1.y + b1.y + c1.y);
        pk.w = pk2(a1.z + b1.z + c1.z, a1.w + b1.w + c1.w);
        *(uint4*)&aF[(size_t)kt * 512 + L * 8] = pk;
    }
    __syncthreads();

    const bf16x8* wf = (const bf16x8*)gws;
    f32x4 acc[2];
    #pragma unroll
    for (int p = 0; p < 2; ++p) acc[p] = (f32x4){0.f, 0.f, 0.f, 0.f};
    #pragma unroll
    for (int kt = 0; kt < 8; ++kt) {
        bf16x8 a = *(const bf16x8*)&aF[kt * 512 + lane * 8];
        #pragma unroll
        for (int p = 0; p < 2; ++p) {
            int nt = half * 8 + wid * 2 + p;
            bf16x8 w = wf[(size_t)((mat * 16 + nt) * 8 + kt) * 64 + lane];
            acc[p] = __builtin_amdgcn_mfma_f32_16x16x32_bf16(a, w, acc[p], 0, 0, 0);
        }
    }
    #pragma unroll
    for (int p = 0; p < 2; ++p) {
        int nt = half * 8 + wid * 2 + p;
        #pragma unroll
        for (int r = 0; r < 4; ++r)
            G[((size_t)mat * ROWS + mt * 16 + q * 4 + r) * H_ + nt * 16 + col] = acc[p][r];
    }
}

// Per-row GRU gates + output MLP. 1 row per block (400 blocks).
__global__ __launch_bounds__(256) void gruout_kernel(
        const float* __restrict__ inputs, const float* __restrict__ G,
        float* __restrict__ hidden, unsigned short* __restrict__ hidden_bf,
        const unsigned short* __restrict__ gruw,
        const float* __restrict__ w_ir, const float* __restrict__ b_ir,
        const float* __restrict__ w_ii, const float* __restrict__ b_ii,
        const float* __restrict__ w_in, const float* __restrict__ b_in,
        const float* __restrict__ b_o1, const float* __restrict__ b_o2,
        const float* __restrict__ w_o3, const float* __restrict__ b_o3,
        float* __restrict__ out, int t) {
    __shared__ float hnL[256];
    __shared__ float p1L[256];
    __shared__ float p2L[256];
    __shared__ float insS[8];
    __shared__ float red[4][6];

    int row = blockIdx.x;
    int b = row / 50, n = row - b * 50;
    int h = threadIdx.x;
    int lane = h & 63, wid = h >> 6;

    const unsigned short* wo1 = gruw;
    const unsigned short* wo2 = gruw + 65536;

    const float* src = (t == 0) ? inputs : out;
    int tt = (t == 0) ? 0 : (t - 1);
    if (h < 6) insS[h] = src[(((size_t)b * T_ + tt) * N_ + n) * IN_ + h];
    __syncthreads();

    {
        float gr = G[(size_t)row * H_ + h];
        float gi = G[(size_t)(ROWS + row) * H_ + h];
        float gn = G[(size_t)(2 * ROWS + row) * H_ + h];
        float xr = b_ir[h], xi = b_ii[h], xn = b_in[h];
        #pragma unroll
        for (int c = 0; c < 6; ++c) {
            float iv = insS[c];
            xr += w_ir[h * 6 + c] * iv;
            xi += w_ii[h * 6 + c] * iv;
            xn += w_in[h * 6 + c] * iv;
        }
        float rg = sigmoid_fast(xr + gr);
        float ig = sigmoid_fast(xi + gi);
        float nn = tanh_fast(xn + rg * gn);
        size_t hoff = (size_t)row * H_ + h;
        float hold = hidden[hoff];
        float hnew = (1.0f - ig) * nn + ig * hold;
        hidden[hoff] = hnew;
        hidden_bf[hoff] = f2bf(hnew);
        hnL[h] = hnew;
    }
    __syncthreads();
    {
        float a = b_o1[h];
        for (int k = 0; k < 256; k += 8) {
            uint4 uw = *(const uint4*)&wo1[h * 256 + k];
            float w[8];
            unpk8(uw, w);
            #pragma unroll
            for (int j = 0; j < 8; ++j) a += w[j] * hnL[k + j];
        }
        p1L[h] = fmaxf(a, 0.0f);
    }
    __syncthreads();
    {
        float a = b_o2[h];
        for (int k = 0; k < 256; k += 8) {
            uint4 uw = *(const uint4*)&wo2[h * 256 + k];
            float w[8];
            unpk8(uw, w);
            #pragma unroll
            for (int j = 0; j < 8; ++j) a += w[j] * p1L[k + j];
        }
        p2L[h] = fmaxf(a, 0.0f);
    }
    __syncthreads();
    {
        float v = p2L[h];
        float part[6];
        #pragma unroll
        for (int c = 0; c < 6; ++c) part[c] = w_o3[c * 256 + h] * v;
        #pragma unroll
        for (int off = 1; off < 64; off <<= 1)
            #pragma unroll
            for (int c = 0; c < 6; ++c) part[c] += __shfl_xor(part[c], off);
        if (lane == 0)
            #pragma unroll
            for (int c = 0; c < 6; ++c) red[wid][c] = part[c];
    }
    __syncthreads();
    if (h < 6) {
        float acc = b_o3[h] + red[0][h] + red[1][h] + red[2][h] + red[3][h];
        out[(((size_t)b * T_ + t) * N_ + n) * IN_ + h] = insS[h] + acc;
    }
}

extern "C" void kernel_launch(void* const* d_in, const int* in_sizes, int n_in,
                              void* d_out, int out_size, void* d_ws, size_t ws_size,
                              hipStream_t stream) {
    const float* inputs = (const float*)d_in[0];
    const float* edges  = (const float*)d_in[1];
    const float* msg_w1 = (const float*)d_in[2];
    const float* msg_b1 = (const float*)d_in[3];
    const float* msg_w2 = (const float*)d_in[4];
    const float* msg_b2 = (const float*)d_in[5];
    const float* w_hr = (const float*)d_in[6];
    const float* w_hi = (const float*)d_in[7];
    const float* w_hh = (const float*)d_in[8];
    const float* w_ir = (const float*)d_in[9];
    const float* b_ir = (const float*)d_in[10];
    const float* w_ii = (const float*)d_in[11];
    const float* b_ii = (const float*)d_in[12];
    const float* w_in = (const float*)d_in[13];
    const float* b_in = (const float*)d_in[14];
    const float* w_o1 = (const float*)d_in[15];
    const float* b_o1 = (const float*)d_in[16];
    const float* w_o2 = (const float*)d_in[17];
    const float* b_o2 = (const float*)d_in[18];
    const float* w_o3 = (const float*)d_in[19];
    const float* b_o3 = (const float*)d_in[20];
    float* out = (float*)d_out;

    char* ws = (char*)d_ws;
    float* hidden            = (float*)(ws);                       // 409,600 B
    unsigned short* hidden_bf= (unsigned short*)(ws + 409600);     // 204,800 B
    float* UV                = (float*)(ws + 614400);              // 2,457,600 B
    float* aggP              = (float*)(ws + 3072000);             // 1,228,800 B
    float* G                 = (float*)(ws + 4300800);             // 1,228,800 B
    unsigned short* w1s      = (unsigned short*)(ws + 5529600);    // 786,432 B
    unsigned short* w2s      = (unsigned short*)(ws + 6316032);    // 393,216 B
    unsigned short* gws      = (unsigned short*)(ws + 6709248);    // 393,216 B
    unsigned short* gruw     = (unsigned short*)(ws + 7102464);    // 262,144 B

    // setup: swizzle all weights + zero hidden/hidden_bf. 1,071,104 items / 256 = 4184.
    swizzle_weights<<<dim3(4184), dim3(256), 0, stream>>>(
        msg_w1, msg_w2, w_hr, w_hi, w_hh, w_o1, w_o2, w1s, w2s, gws, gruw,
        (unsigned int*)ws);

    for (int t = 0; t < T_; ++t) {
        uv_kernel<<<dim3(150), dim3(256), 0, stream>>>(hidden_bf, w1s, msg_b1, UV);
        msgagg_kernel<<<dim3(1200), dim3(256), 0, stream>>>(
            UV, edges, w2s, msg_b2, aggP, t);
        gates_kernel<<<dim3(150), dim3(256), 0, stream>>>(aggP, gws, G);
        gruout_kernel<<<dim3(400), dim3(256), 0, stream>>>(
            inputs, G, hidden, hidden_bf, gruw,
            w_ir, b_ir, w_ii, b_ii, w_in, b_in, b_o1, b_o2, w_o3, b_o3, out, t);
    }
}

// Round 6
// 595.374 us; speedup vs baseline: 4.4029x; 1.0900x over previous
//
#include <hip/hip_runtime.h>
#include <hip/hip_bf16.h>
#include <stdint.h>

#define B_ 8
#define T_ 10
#define N_ 50
#define IN_ 6
#define H_ 256
#define K_ 4
#define E_ 2450
#define ROWS 400           // B_*N_
#define AP 102400          // ROWS*H_

typedef __attribute__((ext_vector_type(8))) __bf16 bf16x8;
typedef __attribute__((ext_vector_type(4))) float f32x4;

__device__ __forceinline__ unsigned short f2bf(float x) {
    unsigned int u = __float_as_uint(x);
    u = (u + 0x7fffu + ((u >> 16) & 1u)) >> 16;   // RNE
    return (unsigned short)u;
}
__device__ __forceinline__ unsigned pk2(float a, float b) {
    return (unsigned)f2bf(a) | ((unsigned)f2bf(b) << 16);
}
__device__ __forceinline__ float rcp_fast(float x) { return __builtin_amdgcn_rcpf(x); }
__device__ __forceinline__ float tanh_fast(float x) {
    float e = __expf(2.0f * x);
    return 1.0f - 2.0f * rcp_fast(e + 1.0f);
}
__device__ __forceinline__ float sigmoid_fast(float x) {
    return rcp_fast(1.0f + __expf(-x));
}

// Swizzle: w1s | w2s | gws (whr/whi/whh B-frag) | wos (wo1/wo2 B-frag) | zero hidden.
__global__ __launch_bounds__(256) void swizzle_weights(
        const float* __restrict__ w1, const float* __restrict__ w2,
        const float* __restrict__ whr, const float* __restrict__ whi,
        const float* __restrict__ whh, const float* __restrict__ wo1,
        const float* __restrict__ wo2,
        unsigned short* __restrict__ w1s, unsigned short* __restrict__ w2s,
        unsigned short* __restrict__ gws, unsigned short* __restrict__ wos,
        unsigned int* __restrict__ zero_region) {
    const int W1N = 3 * 16 * 16 * 64 * 8;   // 393216
    const int W2N = 3 * 16 * 8 * 64 * 8;    // 196608
    const int GWN = 3 * 65536;              // 196608
    const int WON = 2 * 65536;              // 131072
    int idx = blockIdx.x * 256 + threadIdx.x;
    if (idx < W1N) {
        int j = idx & 7, L = (idx >> 3) & 63, kt = (idx >> 9) & 15;
        int nt = (idx >> 13) & 15, i = idx >> 17;
        int n = nt * 16 + (L & 15);
        int k = kt * 32 + ((L >> 4) << 3) + j;
        w1s[idx] = f2bf(w1[((size_t)(i + 1) * H_ + n) * (2 * H_) + k]);
    } else if (idx < W1N + W2N) {
        int t = idx - W1N;
        int j = t & 7, L = (t >> 3) & 63, kt = (t >> 9) & 7;
        int nt = (t >> 12) & 15, i = t >> 16;
        int n = nt * 16 + (L & 15);
        int k = kt * 32 + ((L >> 4) << 3) + j;
        w2s[t] = f2bf(w2[((size_t)(i + 1) * H_ + n) * H_ + k]);
    } else if (idx < W1N + W2N + GWN) {
        int t = idx - (W1N + W2N);
        int j = t & 7, L = (t >> 3) & 63, kt = (t >> 9) & 7;
        int nt = (t >> 12) & 15, mat = t >> 16;
        int n = nt * 16 + (L & 15);
        int k = kt * 32 + ((L >> 4) << 3) + j;
        const float* src = (mat == 0) ? whr : (mat == 1) ? whi : whh;
        gws[t] = f2bf(src[(size_t)n * H_ + k]);
    } else if (idx < W1N + W2N + GWN + WON) {
        int t = idx - (W1N + W2N + GWN);
        int j = t & 7, L = (t >> 3) & 63, kt = (t >> 9) & 7;
        int nt = (t >> 12) & 15, g = t >> 16;
        int n = nt * 16 + (L & 15);
        int k = kt * 32 + ((L >> 4) << 3) + j;
        const float* src = (g == 0) ? wo1 : wo2;
        wos[t] = f2bf(src[(size_t)n * H_ + k]);
    } else {
        int t = idx - (W1N + W2N + GWN + WON);
        if (t < 153600) zero_region[t] = 0u;
    }
}

// U/V per node. U half gets b1 pre-folded.
__global__ __launch_bounds__(256) void uv_kernel(
        const unsigned short* __restrict__ hb, const unsigned short* __restrict__ w1s,
        const float* __restrict__ b1, float* __restrict__ UV) {
    int mm = blockIdx.x / 6;
    int tyh = blockIdx.x % 6;
    int ty = tyh >> 1, half = tyh & 1;
    int lane = threadIdx.x & 63, wid = threadIdx.x >> 6;
    int col = lane & 15, q = lane >> 4;
    const bf16x8* w1f = (const bf16x8*)w1s;

    f32x4 acc[4];
    #pragma unroll
    for (int u = 0; u < 4; ++u) acc[u] = (f32x4){0.f, 0.f, 0.f, 0.f};
    #pragma unroll
    for (int kt = 0; kt < 8; ++kt) {
        bf16x8 a = *(const bf16x8*)&hb[(size_t)(mm * 16 + col) * H_ + kt * 32 + q * 8];
        #pragma unroll
        for (int u = 0; u < 4; ++u) {
            bf16x8 w = w1f[(size_t)((ty * 16 + wid * 4 + u) * 16 + half * 8 + kt) * 64 + lane];
            acc[u] = __builtin_amdgcn_mfma_f32_16x16x32_bf16(a, w, acc[u], 0, 0, 0);
        }
    }
    #pragma unroll
    for (int u = 0; u < 4; ++u) {
        float bias = (half == 0) ? b1[(ty + 1) * H_ + (wid * 4 + u) * 16 + col] : 0.0f;
        #pragma unroll
        for (int r = 0; r < 4; ++r)
            UV[((size_t)(mm * 16 + q * 4 + r) * 3 + ty) * 512 + half * 256 +
               (wid * 4 + u) * 16 + col] = acc[u][r] + bias;
    }
}

// Fused m1-build + GEMM2 + sender-reduction. Block = (ty, b, recv r).
// Output scaled by 1/147 = (1/3 msg norm) * (1/49 agg norm).
__global__ __launch_bounds__(256, 4) void msgagg_kernel(
        const float* __restrict__ UV, const float* __restrict__ edges,
        const unsigned short* __restrict__ w2s,
        const float* __restrict__ b2, float* __restrict__ aggP, int t) {
    __shared__ unsigned short m1F[32 * 512];
    __shared__ float relS[64];

    int ty = blockIdx.x / 400;
    int rem = blockIdx.x - ty * 400;
    int b = rem / 50;
    int r = rem - b * 50;
    int tid = threadIdx.x;
    int lane = tid & 63, wid = tid >> 6;
    int col = lane & 15, q = lane >> 4;

    if (tid < 64) {
        float v = 0.0f;
        if (tid < 50 && tid != r) {
            int e = tid * 49 + (r > tid ? r - 1 : r);
            v = edges[(((size_t)b * T_ + t) * E_ + e) * K_ + ty + 1];
        }
        relS[tid] = v;
    }

    {
        int row = wid * 16 + col;
        int sv = row < N_ ? row : N_ - 1;
        float fl = (row < N_) ? 1.0f : 0.0f;
        const float* Vrow = &UV[((size_t)(b * N_ + sv) * 3 + ty) * 512 + 256 + q * 8];
        const float* Urow = &UV[((size_t)(b * N_ + r) * 3 + ty) * 512 + q * 8];
        #pragma unroll
        for (int kt = 0; kt < 8; ++kt) {
            float4 v0 = *(const float4*)(Vrow + kt * 32);
            float4 v1 = *(const float4*)(Vrow + kt * 32 + 4);
            float4 u0 = *(const float4*)(Urow + kt * 32);
            float4 u1 = *(const float4*)(Urow + kt * 32 + 4);
            float m0 = tanh_fast(u0.x + v0.x) * fl;
            float m1 = tanh_fast(u0.y + v0.y) * fl;
            float m2 = tanh_fast(u0.z + v0.z) * fl;
            float m3 = tanh_fast(u0.w + v0.w) * fl;
            float m4 = tanh_fast(u1.x + v1.x) * fl;
            float m5 = tanh_fast(u1.y + v1.y) * fl;
            float m6 = tanh_fast(u1.z + v1.z) * fl;
            float m7 = tanh_fast(u1.w + v1.w) * fl;
            uint4 pk;
            pk.x = pk2(m0, m1); pk.y = pk2(m2, m3);
            pk.z = pk2(m4, m5); pk.w = pk2(m6, m7);
            *(uint4*)&m1F[(wid * 8 + kt) * 512 + lane * 8] = pk;
        }
    }
    __syncthreads();

    const bf16x8* w2f = (const bf16x8*)w2s;
    f32x4 acc[4][4];
    #pragma unroll
    for (int mt = 0; mt < 4; ++mt)
        #pragma unroll
        for (int u = 0; u < 4; ++u) acc[mt][u] = (f32x4){0.f, 0.f, 0.f, 0.f};

    #pragma unroll
    for (int kt = 0; kt < 8; ++kt) {
        bf16x8 a0 = *(const bf16x8*)&m1F[(0 * 8 + kt) * 512 + lane * 8];
        bf16x8 a1 = *(const bf16x8*)&m1F[(1 * 8 + kt) * 512 + lane * 8];
        bf16x8 a2 = *(const bf16x8*)&m1F[(2 * 8 + kt) * 512 + lane * 8];
        bf16x8 a3 = *(const bf16x8*)&m1F[(3 * 8 + kt) * 512 + lane * 8];
        #pragma unroll
        for (int u = 0; u < 4; ++u) {
            bf16x8 w = w2f[(size_t)((ty * 16 + wid * 4 + u) * 8 + kt) * 64 + lane];
            acc[0][u] = __builtin_amdgcn_mfma_f32_16x16x32_bf16(a0, w, acc[0][u], 0, 0, 0);
            acc[1][u] = __builtin_amdgcn_mfma_f32_16x16x32_bf16(a1, w, acc[1][u], 0, 0, 0);
            acc[2][u] = __builtin_amdgcn_mfma_f32_16x16x32_bf16(a2, w, acc[2][u], 0, 0, 0);
            acc[3][u] = __builtin_amdgcn_mfma_f32_16x16x32_bf16(a3, w, acc[3][u], 0, 0, 0);
        }
    }
    #pragma unroll
    for (int u = 0; u < 4; ++u) {
        float bias = b2[(ty + 1) * H_ + (wid * 4 + u) * 16 + col];
        float sum = 0.0f;
        #pragma unroll
        for (int mt = 0; mt < 4; ++mt)
            #pragma unroll
            for (int rg = 0; rg < 4; ++rg) {
                int row = mt * 16 + q * 4 + rg;
                sum += tanh_fast(acc[mt][u][rg] + bias) * relS[row];
            }
        sum += __shfl_xor(sum, 16);
        sum += __shfl_xor(sum, 32);
        if (lane < 16)
            aggP[(size_t)ty * AP + (size_t)(b * N_ + r) * H_ +
                 (wid * 4 + u) * 16 + col] = sum * (1.0f / 147.0f);
    }
}

// Fused node kernel: gates GEMM (3 mats) + GRU elementwise + o1/o2 MFMA MLP + o3.
// Block = one 16-row m-tile (25 blocks). All work row-local after aggP.
__global__ __launch_bounds__(256) void node_kernel(
        const float* __restrict__ inputs, const float* __restrict__ aggP,
        const unsigned short* __restrict__ gws, const unsigned short* __restrict__ wos,
        float* __restrict__ hidden, unsigned short* __restrict__ hidden_bf,
        const float* __restrict__ w_ir, const float* __restrict__ b_ir,
        const float* __restrict__ w_ii, const float* __restrict__ b_ii,
        const float* __restrict__ w_in, const float* __restrict__ b_in,
        const float* __restrict__ b_o1, const float* __restrict__ b_o2,
        const float* __restrict__ w_o3, const float* __restrict__ b_o3,
        float* __restrict__ out, int t) {
    __shared__ unsigned short aggF[8 * 512];   // agg A-frags (16 rows x 256 k)
    __shared__ unsigned short hnF[8 * 512];    // hidden-new A-frags
    __shared__ unsigned short p1F[8 * 512];    // p1 A-frags
    __shared__ float p2L[16 * 260];            // p2 fp32 (padded)
    __shared__ float insS[16 * 6];

    int mm = blockIdx.x;
    int tid = threadIdx.x;
    int lane = tid & 63, wid = tid >> 6;
    int col = lane & 15, q = lane >> 4;

    const float* src = (t == 0) ? inputs : out;
    int tt = (t == 0) ? 0 : (t - 1);

    // stage agg A-frags (sum of 3 partials) + ins rows
    #pragma unroll
    for (int s = 0; s < 2; ++s) {
        int slot = tid + s * 256;
        int kt = slot >> 6, L = slot & 63;
        int row = mm * 16 + (L & 15);
        int k0 = kt * 32 + ((L >> 4) << 3);
        const float* p = &aggP[(size_t)row * H_ + k0];
        float4 a0 = *(const float4*)(p);
        float4 a1 = *(const float4*)(p + 4);
        float4 b0 = *(const float4*)(p + AP);
        float4 b1 = *(const float4*)(p + AP + 4);
        float4 c0 = *(const float4*)(p + 2 * AP);
        float4 c1 = *(const float4*)(p + 2 * AP + 4);
        uint4 pk;
        pk.x = pk2(a0.x + b0.x + c0.x, a0.y + b0.y + c0.y);
        pk.y = pk2(a0.z + b0.z + c0.z, a0.w + b0.w + c0.w);
        pk.z = pk2(a1.x + b1.x + c1.x, a1.y + b1.y + c1.y);
        pk.w = pk2(a1.z + b1.z + c1.z, a1.w + b1.w + c1.w);
        *(uint4*)&aggF[(size_t)kt * 512 + L * 8] = pk;
    }
    if (tid < 96) {
        int rl = tid / 6, c = tid - rl * 6;
        int row = mm * 16 + rl;
        int b = row / 50, n = row - b * 50;
        insS[rl * 6 + c] = src[(((size_t)b * T_ + tt) * N_ + n) * IN_ + c];
    }
    __syncthreads();

    // gates GEMM: acc[mat][u] over wave's n-tiles wid*4+u
    const bf16x8* gwf = (const bf16x8*)gws;
    f32x4 acc[3][4];
    #pragma unroll
    for (int m = 0; m < 3; ++m)
        #pragma unroll
        for (int u = 0; u < 4; ++u) acc[m][u] = (f32x4){0.f, 0.f, 0.f, 0.f};
    #pragma unroll
    for (int kt = 0; kt < 8; ++kt) {
        bf16x8 a = *(const bf16x8*)&aggF[kt * 512 + lane * 8];
        #pragma unroll
        for (int m = 0; m < 3; ++m)
            #pragma unroll
            for (int u = 0; u < 4; ++u) {
                bf16x8 w = gwf[(size_t)((m * 16 + wid * 4 + u) * 8 + kt) * 64 + lane];
                acc[m][u] = __builtin_amdgcn_mfma_f32_16x16x32_bf16(a, w, acc[m][u], 0, 0, 0);
            }
    }

    // GRU elementwise in C-frag registers; write hidden + hnF A-frags
    #pragma unroll
    for (int u = 0; u < 4; ++u) {
        int h = (wid * 4 + u) * 16 + col;
        float bir = b_ir[h], bii = b_ii[h], bin_ = b_in[h];
        float wir[6], wii[6], win[6];
        #pragma unroll
        for (int c = 0; c < 6; ++c) {
            wir[c] = w_ir[h * 6 + c];
            wii[c] = w_ii[h * 6 + c];
            win[c] = w_in[h * 6 + c];
        }
        #pragma unroll
        for (int rg = 0; rg < 4; ++rg) {
            int rl = q * 4 + rg;
            int row = mm * 16 + rl;
            float xr = bir, xi = bii, xn = bin_;
            #pragma unroll
            for (int c = 0; c < 6; ++c) {
                float iv = insS[rl * 6 + c];
                xr += wir[c] * iv;
                xi += wii[c] * iv;
                xn += win[c] * iv;
            }
            float rgate = sigmoid_fast(xr + acc[0][u][rg]);
            float igate = sigmoid_fast(xi + acc[1][u][rg]);
            float nn = tanh_fast(xn + rgate * acc[2][u][rg]);
            size_t off = (size_t)row * H_ + h;
            float hold = hidden[off];
            float hnew = (1.0f - igate) * nn + igate * hold;
            hidden[off] = hnew;
            hidden_bf[off] = f2bf(hnew);
            hnF[(h >> 5) * 512 + (((h >> 3) & 3) * 16 + rl) * 8 + (h & 7)] = f2bf(hnew);
        }
    }
    __syncthreads();

    // o1 GEMM -> relu -> p1F
    const bf16x8* wof = (const bf16x8*)wos;
    f32x4 a1v[4];
    #pragma unroll
    for (int u = 0; u < 4; ++u) a1v[u] = (f32x4){0.f, 0.f, 0.f, 0.f};
    #pragma unroll
    for (int kt = 0; kt < 8; ++kt) {
        bf16x8 a = *(const bf16x8*)&hnF[kt * 512 + lane * 8];
        #pragma unroll
        for (int u = 0; u < 4; ++u) {
            bf16x8 w = wof[(size_t)((wid * 4 + u) * 8 + kt) * 64 + lane];
            a1v[u] = __builtin_amdgcn_mfma_f32_16x16x32_bf16(a, w, a1v[u], 0, 0, 0);
        }
    }
    #pragma unroll
    for (int u = 0; u < 4; ++u) {
        int h = (wid * 4 + u) * 16 + col;
        float bo = b_o1[h];
        #pragma unroll
        for (int rg = 0; rg < 4; ++rg) {
            int rl = q * 4 + rg;
            float v = fmaxf(a1v[u][rg] + bo, 0.0f);
            p1F[(h >> 5) * 512 + (((h >> 3) & 3) * 16 + rl) * 8 + (h & 7)] = f2bf(v);
        }
    }
    __syncthreads();

    // o2 GEMM -> relu -> p2L
    f32x4 a2v[4];
    #pragma unroll
    for (int u = 0; u < 4; ++u) a2v[u] = (f32x4){0.f, 0.f, 0.f, 0.f};
    #pragma unroll
    for (int kt = 0; kt < 8; ++kt) {
        bf16x8 a = *(const bf16x8*)&p1F[kt * 512 + lane * 8];
        #pragma unroll
        for (int u = 0; u < 4; ++u) {
            bf16x8 w = wof[(size_t)((16 + wid * 4 + u) * 8 + kt) * 64 + lane];
            a2v[u] = __builtin_amdgcn_mfma_f32_16x16x32_bf16(a, w, a2v[u], 0, 0, 0);
        }
    }
    #pragma unroll
    for (int u = 0; u < 4; ++u) {
        int h = (wid * 4 + u) * 16 + col;
        float bo = b_o2[h];
        #pragma unroll
        for (int rg = 0; rg < 4; ++rg) {
            int rl = q * 4 + rg;
            p2L[rl * 260 + h] = fmaxf(a2v[u][rg] + bo, 0.0f);
        }
    }
    __syncthreads();

    // o3: out[row][c] = ins + b_o3[c] + p2[row] . w_o3[c]
    if (tid < 96) {
        int rl = tid / 6, c = tid - rl * 6;
        int row = mm * 16 + rl;
        float acc3 = b_o3[c];
        for (int k = 0; k < 256; k += 4) {
            float4 w = *(const float4*)&w_o3[c * 256 + k];
            float4 p = *(const float4*)&p2L[rl * 260 + k];
            acc3 += w.x * p.x + w.y * p.y + w.z * p.z + w.w * p.w;
        }
        int b = row / 50, n = row - b * 50;
        out[(((size_t)b * T_ + t) * N_ + n) * IN_ + c] = insS[rl * 6 + c] + acc3;
    }
}

extern "C" void kernel_launch(void* const* d_in, const int* in_sizes, int n_in,
                              void* d_out, int out_size, void* d_ws, size_t ws_size,
                              hipStream_t stream) {
    const float* inputs = (const float*)d_in[0];
    const float* edges  = (const float*)d_in[1];
    const float* msg_w1 = (const float*)d_in[2];
    const float* msg_b1 = (const float*)d_in[3];
    const float* msg_w2 = (const float*)d_in[4];
    const float* msg_b2 = (const float*)d_in[5];
    const float* w_hr = (const float*)d_in[6];
    const float* w_hi = (const float*)d_in[7];
    const float* w_hh = (const float*)d_in[8];
    const float* w_ir = (const float*)d_in[9];
    const float* b_ir = (const float*)d_in[10];
    const float* w_ii = (const float*)d_in[11];
    const float* b_ii = (const float*)d_in[12];
    const float* w_in = (const float*)d_in[13];
    const float* b_in = (const float*)d_in[14];
    const float* w_o1 = (const float*)d_in[15];
    const float* b_o1 = (const float*)d_in[16];
    const float* w_o2 = (const float*)d_in[17];
    const float* b_o2 = (const float*)d_in[18];
    const float* w_o3 = (const float*)d_in[19];
    const float* b_o3 = (const float*)d_in[20];
    float* out = (float*)d_out;

    char* ws = (char*)d_ws;
    float* hidden            = (float*)(ws);                       // 409,600 B
    unsigned short* hidden_bf= (unsigned short*)(ws + 409600);     // 204,800 B
    float* UV                = (float*)(ws + 614400);              // 2,457,600 B
    float* aggP              = (float*)(ws + 3072000);             // 1,228,800 B
    unsigned short* w1s      = (unsigned short*)(ws + 4300800);    // 786,432 B
    unsigned short* w2s      = (unsigned short*)(ws + 5087232);    // 393,216 B
    unsigned short* gws      = (unsigned short*)(ws + 5480448);    // 393,216 B
    unsigned short* wos      = (unsigned short*)(ws + 5873664);    // 262,144 B

    // setup: swizzle all weights + zero hidden/hidden_bf. 1,071,104 items / 256 = 4184.
    swizzle_weights<<<dim3(4184), dim3(256), 0, stream>>>(
        msg_w1, msg_w2, w_hr, w_hi, w_hh, w_o1, w_o2, w1s, w2s, gws, wos,
        (unsigned int*)ws);

    for (int t = 0; t < T_; ++t) {
        uv_kernel<<<dim3(150), dim3(256), 0, stream>>>(hidden_bf, w1s, msg_b1, UV);
        msgagg_kernel<<<dim3(1200), dim3(256), 0, stream>>>(
            UV, edges, w2s, msg_b2, aggP, t);
        node_kernel<<<dim3(25), dim3(256), 0, stream>>>(
            inputs, aggP, gws, wos, hidden, hidden_bf,
            w_ir, b_ir, w_ii, b_ii, w_in, b_in, b_o1, b_o2, w_o3, b_o3, out, t);
    }
}